// Round 1
// baseline (14709.882 us; speedup 1.0000x reference)
//
#include <hip/hip_runtime.h>
#include <cstdint>
#include <cstddef>

#define B_  4
#define S_  512
#define T_  1023
#define D_  1024
#define H_  16
#define DH_ 64
#define F_  4096
#define L_  4

// ---------------------------------------------------------------------------
// Generic fp32 GEMM: C[M,N] = op(A[M,K] @ W[K,N] + bias[N]), op = ReLU opt.
// 64x64 tile, 256 threads (16x16 logical), 4x4 per-thread microtile, K-tile 16.
// Correctness-first; MFMA port comes later.
// ---------------------------------------------------------------------------
__global__ __launch_bounds__(256) void gemm_f32(
    const float* __restrict__ A, const float* __restrict__ W,
    const float* __restrict__ bias, float* __restrict__ C,
    int M, int K, int N, int relu)
{
    __shared__ float As[64][17];
    __shared__ float Ws[16][65];
    const int tid = threadIdx.x;
    const int tx = tid & 15;
    const int ty = tid >> 4;
    const int row0 = blockIdx.y * 64;
    const int col0 = blockIdx.x * 64;

    float acc[4][4];
    #pragma unroll
    for (int i = 0; i < 4; ++i)
        #pragma unroll
        for (int j = 0; j < 4; ++j) acc[i][j] = 0.f;

    for (int kt = 0; kt < K; kt += 16) {
        #pragma unroll
        for (int i = 0; i < 4; ++i) {           // A tile 64x16
            int e = tid + i * 256;
            int r = e >> 4, c = e & 15;
            int gr = row0 + r;
            As[r][c] = (gr < M) ? A[(size_t)gr * K + kt + c] : 0.f;
        }
        #pragma unroll
        for (int i = 0; i < 4; ++i) {           // W tile 16x64
            int e = tid + i * 256;
            int r = e >> 6, c = e & 63;
            int gc = col0 + c;
            Ws[r][c] = (gc < N) ? W[(size_t)(kt + r) * N + gc] : 0.f;
        }
        __syncthreads();
        #pragma unroll
        for (int kk = 0; kk < 16; ++kk) {
            float a[4], w[4];
            #pragma unroll
            for (int i = 0; i < 4; ++i) a[i] = As[ty * 4 + i][kk];
            #pragma unroll
            for (int j = 0; j < 4; ++j) w[j] = Ws[kk][tx * 4 + j];
            #pragma unroll
            for (int i = 0; i < 4; ++i)
                #pragma unroll
                for (int j = 0; j < 4; ++j)
                    acc[i][j] = fmaf(a[i], w[j], acc[i][j]);
        }
        __syncthreads();
    }

    #pragma unroll
    for (int i = 0; i < 4; ++i) {
        int r = row0 + ty * 4 + i;
        if (r >= M) continue;
        #pragma unroll
        for (int j = 0; j < 4; ++j) {
            int c = col0 + tx * 4 + j;
            if (c >= N) continue;
            float v = acc[i][j] + bias[c];
            if (relu) v = fmaxf(v, 0.f);
            C[(size_t)r * N + c] = v;
        }
    }
}

// ---------------------------------------------------------------------------
// Flash-style causal self-attention, fp32.
// qkv: [B*T, 3*D] (q | k | v). out: [B*T, D] (heads concatenated).
// grid = (B*H, ceil(T/64)), block = 64 (1 wave). Thread = one query row.
// ---------------------------------------------------------------------------
__global__ __launch_bounds__(64) void attn_kernel(
    const float* __restrict__ qkv, float* __restrict__ out)
{
    const int bh = blockIdx.x;
    const int b = bh >> 4;        // H_ = 16
    const int h = bh & 15;
    const int qt = blockIdx.y;
    const int t = threadIdx.x;
    const int q = qt * 64 + t;
    const bool qvalid = (q < T_);

    __shared__ float Ks[64][65];
    __shared__ float Vs[64][65];
    __shared__ float Ss[64][65];

    const size_t rs = 3 * D_;
    const float* qbase = qkv + (size_t)(b * T_ + (qvalid ? q : 0)) * rs + h * DH_;
    float qr[DH_];
    #pragma unroll
    for (int d = 0; d < DH_; ++d) qr[d] = qvalid ? qbase[d] : 0.f;

    float acc[DH_];
    #pragma unroll
    for (int d = 0; d < DH_; ++d) acc[d] = 0.f;
    float m = -3.0e38f, l = 0.f;

    for (int kt = 0; kt <= qt; ++kt) {
        const int k0 = kt * 64;
        // stage K/V tiles (coalesced across lanes: lane = channel)
        for (int j = 0; j < 64; ++j) {
            int k = k0 + j;
            if (k < T_) {
                const float* kb = qkv + (size_t)(b * T_ + k) * rs + D_ + h * DH_;
                Ks[j][t] = kb[t];
                Vs[j][t] = kb[D_ + t];
            } else {
                Ks[j][t] = 0.f;
                Vs[j][t] = 0.f;
            }
        }
        __syncthreads();

        // scores for this thread's q row
        float mt = -3.0e38f;
        for (int j = 0; j < 64; ++j) {
            float s = 0.f;
            #pragma unroll
            for (int d = 0; d < DH_; ++d) s = fmaf(qr[d], Ks[j][d], s);
            s *= 0.125f;   // 1/sqrt(64)
            int k = k0 + j;
            bool valid = qvalid && (k <= q) && (k < T_);
            s = valid ? s : -3.0e38f;
            Ss[t][j] = s;
            mt = fmaxf(mt, s);
        }
        float mnew = fmaxf(m, mt);
        float alpha = (m < -1.0e37f) ? 0.f : expf(m - mnew);
        float lnew = l * alpha;
        #pragma unroll
        for (int d = 0; d < DH_; ++d) acc[d] *= alpha;
        for (int j = 0; j < 64; ++j) {
            float s = Ss[t][j];
            float p = (s < -1.0e37f) ? 0.f : expf(s - mnew);
            lnew += p;
            #pragma unroll
            for (int d = 0; d < DH_; ++d) acc[d] = fmaf(p, Vs[j][d], acc[d]);
        }
        m = mnew; l = lnew;
        __syncthreads();
    }

    if (qvalid) {
        float inv = 1.f / l;
        float* ob = out + (size_t)(b * T_ + q) * D_ + h * DH_;
        #pragma unroll
        for (int d = 0; d < DH_; ++d) ob[d] = acc[d] * inv;
    }
}

// ---------------------------------------------------------------------------
// x = LN(x + y) * g + beta  (row-wise, D=1024). y may be nullptr (skip add)
// or broadcast (one row added to every row). In-place on x.
// grid = rows, block = 256 (4 elements/thread via float4).
// ---------------------------------------------------------------------------
__global__ __launch_bounds__(256) void add_ln_kernel(
    float* __restrict__ x, const float* __restrict__ y, int ybcast,
    const float* __restrict__ g, const float* __restrict__ beta)
{
    const int row = blockIdx.x;
    const int tid = threadIdx.x;
    float4* xr = reinterpret_cast<float4*>(x + (size_t)row * D_);
    float4 v = xr[tid];
    if (y) {
        const float4* yr = reinterpret_cast<const float4*>(
            ybcast ? y : y + (size_t)row * D_);
        float4 w = yr[tid];
        v.x += w.x; v.y += w.y; v.z += w.z; v.w += w.w;
    }
    float s  = v.x + v.y + v.z + v.w;
    float s2 = v.x * v.x + v.y * v.y + v.z * v.z + v.w * v.w;
    #pragma unroll
    for (int off = 32; off; off >>= 1) {
        s  += __shfl_down(s, off);
        s2 += __shfl_down(s2, off);
    }
    __shared__ float ws[4], ws2[4];
    __shared__ float mu_s, inv_s;
    const int wid = tid >> 6;
    if ((tid & 63) == 0) { ws[wid] = s; ws2[wid] = s2; }
    __syncthreads();
    if (tid == 0) {
        float S  = ws[0] + ws[1] + ws[2] + ws[3];
        float S2 = ws2[0] + ws2[1] + ws2[2] + ws2[3];
        float mu = S * (1.f / (float)D_);
        float var = S2 * (1.f / (float)D_) - mu * mu;
        mu_s = mu;
        inv_s = rsqrtf(var + 1e-5f);
    }
    __syncthreads();
    const float mu = mu_s, inv = inv_s;
    const float4 gg = reinterpret_cast<const float4*>(g)[tid];
    const float4 bb = reinterpret_cast<const float4*>(beta)[tid];
    float4 o;
    o.x = (v.x - mu) * inv * gg.x + bb.x;
    o.y = (v.y - mu) * inv * gg.y + bb.y;
    o.z = (v.z - mu) * inv * gg.z + bb.z;
    o.w = (v.w - mu) * inv * gg.w + bb.w;
    xr[tid] = o;
}

// ---------------------------------------------------------------------------
// Interleave obs/act tokens into x[B*T, D] and add (bug-faithful) PE:
// pe[b, 2i] = sin(b*div_i), pe[b, 2i+1] = cos(b*div_i); batch-indexed.
// grid = B*T rows, block = 256 (4 elems/thread, strided).
// ---------------------------------------------------------------------------
__global__ __launch_bounds__(256) void interleave_pe_kernel(
    const float* __restrict__ obs_tok, const float* __restrict__ act_tok,
    float* __restrict__ x)
{
    const int row = blockIdx.x;
    const int b = row / T_;
    const int t = row - b * T_;
    const float* src = (t & 1)
        ? (act_tok + (size_t)(b * (S_ - 1) + (t >> 1)) * D_)
        : (obs_tok + (size_t)(b * S_ + (t >> 1)) * D_);
    float* xr = x + (size_t)row * D_;
    #pragma unroll
    for (int k = 0; k < 4; ++k) {
        int d = threadIdx.x + k * 256;
        float ang = (float)b * expf(-(float)(d & ~1) * (9.210340371976184f / 1024.0f));
        float pe = (d & 1) ? cosf(ang) : sinf(ang);
        xr[d] = src[d] + pe;
    }
}

// ---------------------------------------------------------------------------
// Cross-attention constant: out[l,d] = sum_k ca_b_in[l, 2D+k]*ca_w_out[l,k,d]
//                                      + ca_b_out[l,d].
// (zero memory token => CA output is a per-layer constant vector)
// grid = L*D/256, block = 256.
// ---------------------------------------------------------------------------
__global__ __launch_bounds__(256) void ca_const_kernel(
    const float* __restrict__ ca_b_in, const float* __restrict__ ca_w_out,
    const float* __restrict__ ca_b_out, float* __restrict__ out)
{
    const int idx = blockIdx.x * 256 + threadIdx.x;   // l*1024 + d
    const int l = idx >> 10;
    const int d = idx & 1023;
    const float* bv = ca_b_in + (size_t)l * 3 * D_ + 2 * D_;
    const float* w  = ca_w_out + (size_t)l * D_ * D_;
    float s = ca_b_out[(size_t)l * D_ + d];
    for (int k = 0; k < D_; ++k) s = fmaf(bv[k], w[(size_t)k * D_ + d], s);
    out[idx] = s;
}

// ---------------------------------------------------------------------------
extern "C" void kernel_launch(void* const* d_in, const int* in_sizes, int n_in,
                              void* d_out, int out_size, void* d_ws, size_t ws_size,
                              hipStream_t stream)
{
    const float* obs     = (const float*)d_in[0];
    const float* act     = (const float*)d_in[1];
    const float* in_w1   = (const float*)d_in[2];
    const float* in_b1   = (const float*)d_in[3];
    const float* in_w2   = (const float*)d_in[4];
    const float* in_b2   = (const float*)d_in[5];
    const float* in_w3   = (const float*)d_in[6];
    const float* in_b3   = (const float*)d_in[7];
    const float* act_w1  = (const float*)d_in[8];
    const float* act_b1  = (const float*)d_in[9];
    const float* act_w2  = (const float*)d_in[10];
    const float* act_b2  = (const float*)d_in[11];
    const float* act_w3  = (const float*)d_in[12];
    const float* act_b3  = (const float*)d_in[13];
    const float* out_w1  = (const float*)d_in[14];
    const float* out_b1  = (const float*)d_in[15];
    const float* out_w2  = (const float*)d_in[16];
    const float* out_b2  = (const float*)d_in[17];
    const float* out_w3  = (const float*)d_in[18];
    const float* out_b3  = (const float*)d_in[19];
    const float* sa_w_in = (const float*)d_in[20];
    const float* sa_b_in = (const float*)d_in[21];
    const float* sa_w_out= (const float*)d_in[22];
    const float* sa_b_out= (const float*)d_in[23];
    const float* ca_b_in = (const float*)d_in[25];
    const float* ca_w_out= (const float*)d_in[26];
    const float* ca_b_out= (const float*)d_in[27];
    const float* ff_w1   = (const float*)d_in[28];
    const float* ff_b1   = (const float*)d_in[29];
    const float* ff_w2   = (const float*)d_in[30];
    const float* ff_b2   = (const float*)d_in[31];
    const float* ln1_g   = (const float*)d_in[32];
    const float* ln1_b   = (const float*)d_in[33];
    const float* ln2_g   = (const float*)d_in[34];
    const float* ln2_b   = (const float*)d_in[35];
    const float* ln3_g   = (const float*)d_in[36];
    const float* ln3_b   = (const float*)d_in[37];
    const float* lnf_g   = (const float*)d_in[38];
    const float* lnf_b   = (const float*)d_in[39];

    const int MT = B_ * T_;          // 4092
    const int Mo = B_ * S_;          // 2048
    const int Ma = B_ * (S_ - 1);    // 2044

    float* ws = (float*)d_ws;
    size_t off = 0;
    float* x    = ws + off; off += (size_t)MT * D_;        // 4.19M
    float* buf1 = ws + off; off += (size_t)MT * F_;        // 16.76M (qkv/ffn)
    float* buf2 = ws + off; off += (size_t)MT * D_;
    float* buf3 = ws + off; off += (size_t)MT * D_;
    float* ca   = ws + off; off += (size_t)L_ * D_;
    if (ws_size < off * sizeof(float)) return;  // fail cleanly, no corruption

    auto gemm = [&](const float* A, const float* W, const float* bias, float* C,
                    int M, int K, int N, int relu) {
        dim3 g((N + 63) / 64, (M + 63) / 64);
        gemm_f32<<<g, 256, 0, stream>>>(A, W, bias, C, M, K, N, relu);
    };

    // ---- input MLPs ----
    gemm(obs,  in_w1, in_b1, buf2, Mo, 64,  D_, 1);
    gemm(buf2, in_w2, in_b2, buf3, Mo, D_,  D_, 1);
    gemm(buf3, in_w3, in_b3, buf2, Mo, D_,  D_, 0);   // obs_tok -> buf2
    gemm(act,  act_w1, act_b1, buf3, Ma, 16, D_, 1);
    gemm(buf3, act_w2, act_b2, buf1, Ma, D_, D_, 1);
    gemm(buf1, act_w3, act_b3, buf3, Ma, D_, D_, 0);  // act_tok -> buf3

    interleave_pe_kernel<<<MT, 256, 0, stream>>>(buf2, buf3, x);
    ca_const_kernel<<<(L_ * D_) / 256, 256, 0, stream>>>(ca_b_in, ca_w_out, ca_b_out, ca);

    // ---- decoder layers ----
    for (int l = 0; l < L_; ++l) {
        gemm(x, sa_w_in + (size_t)l * D_ * 3 * D_, sa_b_in + (size_t)l * 3 * D_,
             buf1, MT, D_, 3 * D_, 0);                               // qkv
        attn_kernel<<<dim3(B_ * H_, (T_ + 63) / 64), 64, 0, stream>>>(buf1, buf2);
        gemm(buf2, sa_w_out + (size_t)l * D_ * D_, sa_b_out + (size_t)l * D_,
             buf3, MT, D_, D_, 0);                                   // proj
        add_ln_kernel<<<MT, 256, 0, stream>>>(x, buf3, 0,
             ln1_g + (size_t)l * D_, ln1_b + (size_t)l * D_);
        add_ln_kernel<<<MT, 256, 0, stream>>>(x, ca + (size_t)l * D_, 1,
             ln2_g + (size_t)l * D_, ln2_b + (size_t)l * D_);        // CA (constant)
        gemm(x, ff_w1 + (size_t)l * D_ * F_, ff_b1 + (size_t)l * F_,
             buf1, MT, D_, F_, 1);                                   // ffn up
        gemm(buf1, ff_w2 + (size_t)l * F_ * D_, ff_b2 + (size_t)l * D_,
             buf3, MT, F_, D_, 0);                                   // ffn down
        add_ln_kernel<<<MT, 256, 0, stream>>>(x, buf3, 0,
             ln3_g + (size_t)l * D_, ln3_b + (size_t)l * D_);
    }

    // ---- final norm + output MLP ----
    add_ln_kernel<<<MT, 256, 0, stream>>>(x, nullptr, 0, lnf_g, lnf_b);
    gemm(x,    out_w1, out_b1, buf2, MT, D_, D_, 1);
    gemm(buf2, out_w2, out_b2, buf3, MT, D_, D_, 1);
    gemm(buf3, out_w3, out_b3, (float*)d_out, MT, D_, 16, 0);
}

// Round 2
// 5578.300 us; speedup vs baseline: 2.6370x; 2.6370x over previous
//
#include <hip/hip_runtime.h>
#include <hip/hip_bf16.h>
#include <cstdint>
#include <cstddef>

#define B_  4
#define S_  512
#define T_  1023
#define D_  1024
#define H_  16
#define DH_ 64
#define F_  4096
#define L_  4

typedef float f32x4 __attribute__((ext_vector_type(4)));
typedef __bf16 bf16x8 __attribute__((ext_vector_type(8)));

// ---------------------------------------------------------------------------
// bf16 MFMA GEMM: C[M,N] = op(A[M,K] @ Wt[N,K]^T + bias), op = optional ReLU.
// A: bf16 [M,K] row-major (K%32==0). Wt: bf16 [N,K] (pre-transposed weight).
// Outputs: Cf (fp32) and/or Cb (bf16), either may be null.
// 128x128 tile, BK=32, 256 threads = 4 waves (2x2), each wave 64x64 via
// 4x4 x mfma_f32_16x16x32_bf16. global_load_lds(16B) staging, linear LDS.
// ---------------------------------------------------------------------------
__global__ __launch_bounds__(256) void gemm_bf16(
    const __hip_bfloat16* __restrict__ A, const __hip_bfloat16* __restrict__ Wt,
    const float* __restrict__ bias,
    float* __restrict__ Cf, __hip_bfloat16* __restrict__ Cb,
    int M, int K, int N, int relu)
{
    __shared__ __align__(16) __hip_bfloat16 Asm[128 * 32];
    __shared__ __align__(16) __hip_bfloat16 Bsm[128 * 32];
    const int tid  = threadIdx.x;
    const int lane = tid & 63;
    const int w    = tid >> 6;          // wave 0..3
    const int wr   = w >> 1, wc = w & 1;
    const int l15  = lane & 15, l4 = lane >> 4;
    const int row0 = blockIdx.y * 128;
    const int col0 = blockIdx.x * 128;

    f32x4 acc[4][4] = {};

    auto* ldsA = (__attribute__((address_space(3))) char*)Asm;
    auto* ldsB = (__attribute__((address_space(3))) char*)Bsm;

    for (int kt = 0; kt < K; kt += 32) {
        #pragma unroll
        for (int half = 0; half < 2; ++half) {
            const int ch = half * 256 + w * 64 + lane;      // 16B chunk id
            const int r  = ch >> 2;
            const int c  = (ch & 3) * 8;                    // bf16 elems
            // A tile: rows row0..row0+127, cols kt..kt+31
            int gr = row0 + r; gr = (gr < M) ? gr : (M - 1);
            const __hip_bfloat16* srcA = A + (size_t)gr * K + kt + c;
            __builtin_amdgcn_global_load_lds(
                (const __attribute__((address_space(1))) unsigned*)srcA,
                (__attribute__((address_space(3))) unsigned*)(ldsA + (size_t)(half * 256 + w * 64) * 16),
                16, 0, 0);
            // B tile: Wt rows col0..col0+127, cols kt..kt+31
            int gc = col0 + r; gc = (gc < N) ? gc : (N - 1);
            const __hip_bfloat16* srcB = Wt + (size_t)gc * K + kt + c;
            __builtin_amdgcn_global_load_lds(
                (const __attribute__((address_space(1))) unsigned*)srcB,
                (__attribute__((address_space(3))) unsigned*)(ldsB + (size_t)(half * 256 + w * 64) * 16),
                16, 0, 0);
        }
        __syncthreads();   // drains vmcnt before barrier (compiler-inserted)

        const __hip_bfloat16* ab = Asm + (size_t)(wr * 64 + l15) * 32 + l4 * 8;
        const __hip_bfloat16* bb = Bsm + (size_t)(wc * 64 + l15) * 32 + l4 * 8;
        bf16x8 af[4], bf[4];
        #pragma unroll
        for (int mi = 0; mi < 4; ++mi) af[mi] = *(const bf16x8*)(ab + mi * 16 * 32);
        #pragma unroll
        for (int nj = 0; nj < 4; ++nj) bf[nj] = *(const bf16x8*)(bb + nj * 16 * 32);
        #pragma unroll
        for (int mi = 0; mi < 4; ++mi)
            #pragma unroll
            for (int nj = 0; nj < 4; ++nj)
                acc[mi][nj] = __builtin_amdgcn_mfma_f32_16x16x32_bf16(
                    af[mi], bf[nj], acc[mi][nj], 0, 0, 0);
        __syncthreads();
    }

    // epilogue: C/D layout col = lane&15, row = (lane>>4)*4 + i  [m89-verified]
    #pragma unroll
    for (int nj = 0; nj < 4; ++nj) {
        const int c = col0 + wc * 64 + nj * 16 + l15;
        if (c >= N) continue;
        const float bv = bias[c];
        #pragma unroll
        for (int mi = 0; mi < 4; ++mi) {
            #pragma unroll
            for (int i = 0; i < 4; ++i) {
                const int r = row0 + wr * 64 + mi * 16 + l4 * 4 + i;
                if (r >= M) continue;
                float v = acc[mi][nj][i] + bv;
                if (relu) v = fmaxf(v, 0.f);
                if (Cf) Cf[(size_t)r * N + c] = v;
                if (Cb) Cb[(size_t)r * N + c] = __float2bfloat16(v);
            }
        }
    }
}

// ---------------------------------------------------------------------------
// Weight transpose+convert: W fp32 [K,N] -> Wt bf16 [N,Kpad], zero-fill k>=K.
// grid: ((N+31)/32, (Kpad+31)/32, batch), block 256.
// ---------------------------------------------------------------------------
__global__ __launch_bounds__(256) void transpose_w(
    const float* __restrict__ W, __hip_bfloat16* __restrict__ Wt,
    int K, int N, int Kpad)
{
    __shared__ float t[32][33];
    W  += (size_t)blockIdx.z * K * N;
    Wt += (size_t)blockIdx.z * N * Kpad;
    const int n0 = blockIdx.x * 32, k0 = blockIdx.y * 32;
    const int tx = threadIdx.x & 31, ty = threadIdx.x >> 5;
    #pragma unroll
    for (int i = 0; i < 4; ++i) {
        int r = ty + i * 8;
        int k = k0 + r, n = n0 + tx;
        t[r][tx] = (k < K && n < N) ? W[(size_t)k * N + n] : 0.f;
    }
    __syncthreads();
    #pragma unroll
    for (int i = 0; i < 4; ++i) {
        int r = ty + i * 8;
        int n = n0 + r, k = k0 + tx;
        if (n < N && k < Kpad) Wt[(size_t)n * Kpad + k] = __float2bfloat16(t[tx][r]);
    }
}

// fp32 [M,Kin] -> bf16 [M,Kout], zero-pad cols >= Kin.
__global__ __launch_bounds__(256) void convert_pad(
    const float* __restrict__ in, __hip_bfloat16* __restrict__ out,
    int M, int Kin, int Kout)
{
    int idx = blockIdx.x * 256 + threadIdx.x;
    if (idx >= M * Kout) return;
    int r = idx / Kout, c = idx - r * Kout;
    out[idx] = __float2bfloat16(c < Kin ? in[(size_t)r * Kin + c] : 0.f);
}

// ---------------------------------------------------------------------------
// fp32 causal attention (stopgap until MFMA port). qkv fp32 [B*T, 3D].
// out bf16 [B*T, D]. grid (B*H, 8), block 128: thread = one q row.
// Single-pass softmax without max-tracking (scores O(1) for this network;
// exp(s) cannot overflow; identical math to softmax-with-max).
// ---------------------------------------------------------------------------
__global__ __launch_bounds__(128) void attn_kernel(
    const float* __restrict__ qkv, __hip_bfloat16* __restrict__ out)
{
    const int bh = blockIdx.x;
    const int b = bh >> 4, h = bh & 15;
    const int t = threadIdx.x;
    const int q = blockIdx.y * 128 + t;
    const bool qvalid = q < T_;
    __shared__ float Ks[64][64];
    __shared__ float Vs[64][64];
    const size_t rs = 3 * D_;

    const float* qb = qkv + (size_t)(b * T_ + (qvalid ? q : T_ - 1)) * rs + h * DH_;
    float4 qr[16];
    #pragma unroll
    for (int i = 0; i < 16; ++i) qr[i] = *(const float4*)(qb + i * 4);

    f32x4 acc[16] = {};
    float l = 0.f;
    const int kmax = (blockIdx.y * 128 + 128 < T_) ? (blockIdx.y * 128 + 128) : T_;

    for (int k0 = 0; k0 < kmax; k0 += 64) {
        __syncthreads();
        #pragma unroll
        for (int i = 0; i < 8; ++i) {        // stage K,V: fully coalesced float4
            int f = i * 128 + t;
            int j = f >> 4, c = (f & 15) * 4;
            int gk = k0 + j;
            int gkc = (gk < T_) ? gk : (T_ - 1);
            const float* kb = qkv + (size_t)(b * T_ + gkc) * rs + D_ + h * DH_ + c;
            float4 kv = *(const float4*)kb;
            float4 vv = *(const float4*)(kb + D_);
            if (gk >= T_) { kv.x = kv.y = kv.z = kv.w = 0.f; vv.x = vv.y = vv.z = vv.w = 0.f; }
            *(float4*)&Ks[j][c] = kv;
            *(float4*)&Vs[j][c] = vv;
        }
        __syncthreads();

        if (qvalid && k0 <= q) {
            int jend = q - k0 + 1;
            if (jend > 64) jend = 64;
            for (int j = 0; j < jend; ++j) {
                float s0 = 0.f, s1 = 0.f, s2 = 0.f, s3 = 0.f;
                #pragma unroll
                for (int i = 0; i < 16; ++i) {
                    const float4 kk = *(const float4*)&Ks[j][i * 4];  // broadcast
                    s0 = fmaf(qr[i].x, kk.x, s0);
                    s1 = fmaf(qr[i].y, kk.y, s1);
                    s2 = fmaf(qr[i].z, kk.z, s2);
                    s3 = fmaf(qr[i].w, kk.w, s3);
                }
                const float p = __expf((s0 + s1 + s2 + s3) * 0.125f);
                l += p;
                #pragma unroll
                for (int i = 0; i < 16; ++i) {
                    const float4 vv = *(const float4*)&Vs[j][i * 4];  // broadcast
                    acc[i][0] = fmaf(p, vv.x, acc[i][0]);
                    acc[i][1] = fmaf(p, vv.y, acc[i][1]);
                    acc[i][2] = fmaf(p, vv.z, acc[i][2]);
                    acc[i][3] = fmaf(p, vv.w, acc[i][3]);
                }
            }
        }
    }

    if (qvalid) {
        const float inv = 1.f / l;
        __hip_bfloat16* ob = out + (size_t)(b * T_ + q) * D_ + h * DH_;
        #pragma unroll
        for (int i = 0; i < 16; ++i) {
            ob[i * 4 + 0] = __float2bfloat16(acc[i][0] * inv);
            ob[i * 4 + 1] = __float2bfloat16(acc[i][1] * inv);
            ob[i * 4 + 2] = __float2bfloat16(acc[i][2] * inv);
            ob[i * 4 + 3] = __float2bfloat16(acc[i][3] * inv);
        }
    }
}

// ---------------------------------------------------------------------------
// x = LN(x + y)*g + beta, in-place on x (fp32); optional bf16 copy to xb.
// y nullable; ybcast broadcasts one row. grid = rows, block 256.
// ---------------------------------------------------------------------------
__global__ __launch_bounds__(256) void add_ln_kernel(
    float* __restrict__ x, const float* __restrict__ y, int ybcast,
    const float* __restrict__ g, const float* __restrict__ beta,
    __hip_bfloat16* __restrict__ xb)
{
    const int row = blockIdx.x;
    const int tid = threadIdx.x;
    float4* xr = reinterpret_cast<float4*>(x + (size_t)row * D_);
    float4 v = xr[tid];
    if (y) {
        const float4* yr = reinterpret_cast<const float4*>(
            ybcast ? y : y + (size_t)row * D_);
        float4 wv = yr[tid];
        v.x += wv.x; v.y += wv.y; v.z += wv.z; v.w += wv.w;
    }
    float s  = v.x + v.y + v.z + v.w;
    float s2 = v.x * v.x + v.y * v.y + v.z * v.z + v.w * v.w;
    #pragma unroll
    for (int off = 32; off; off >>= 1) {
        s  += __shfl_down(s, off);
        s2 += __shfl_down(s2, off);
    }
    __shared__ float ws[4], ws2[4];
    __shared__ float mu_s, inv_s;
    const int wid = tid >> 6;
    if ((tid & 63) == 0) { ws[wid] = s; ws2[wid] = s2; }
    __syncthreads();
    if (tid == 0) {
        float S  = ws[0] + ws[1] + ws[2] + ws[3];
        float S2 = ws2[0] + ws2[1] + ws2[2] + ws2[3];
        float mu = S * (1.f / (float)D_);
        float var = S2 * (1.f / (float)D_) - mu * mu;
        mu_s = mu;
        inv_s = rsqrtf(var + 1e-5f);
    }
    __syncthreads();
    const float mu = mu_s, inv = inv_s;
    const float4 gg = reinterpret_cast<const float4*>(g)[tid];
    const float4 bb = reinterpret_cast<const float4*>(beta)[tid];
    float4 o;
    o.x = (v.x - mu) * inv * gg.x + bb.x;
    o.y = (v.y - mu) * inv * gg.y + bb.y;
    o.z = (v.z - mu) * inv * gg.z + bb.z;
    o.w = (v.w - mu) * inv * gg.w + bb.w;
    xr[tid] = o;
    if (xb) {
        __hip_bfloat16* xo = xb + (size_t)row * D_ + tid * 4;
        xo[0] = __float2bfloat16(o.x);
        xo[1] = __float2bfloat16(o.y);
        xo[2] = __float2bfloat16(o.z);
        xo[3] = __float2bfloat16(o.w);
    }
}

// Interleave obs/act tokens + (bug-faithful batch-indexed) PE -> x f32 + bf16.
__global__ __launch_bounds__(256) void interleave_pe_kernel(
    const float* __restrict__ obs_tok, const float* __restrict__ act_tok,
    float* __restrict__ x, __hip_bfloat16* __restrict__ xb)
{
    const int row = blockIdx.x;
    const int b = row / T_;
    const int t = row - b * T_;
    const float* src = (t & 1)
        ? (act_tok + (size_t)(b * (S_ - 1) + (t >> 1)) * D_)
        : (obs_tok + (size_t)(b * S_ + (t >> 1)) * D_);
    float* xr = x + (size_t)row * D_;
    __hip_bfloat16* xo = xb + (size_t)row * D_;
    #pragma unroll
    for (int k = 0; k < 4; ++k) {
        int d = threadIdx.x + k * 256;
        float ang = (float)b * expf(-(float)(d & ~1) * (9.210340371976184f / 1024.0f));
        float pe = (d & 1) ? cosf(ang) : sinf(ang);
        float v = src[d] + pe;
        xr[d] = v;
        xo[d] = __float2bfloat16(v);
    }
}

// CA constant: out[l,d] = sum_k ca_b_in[l,2D+k]*ca_w_out[l,k,d] + ca_b_out[l,d]
__global__ __launch_bounds__(256) void ca_const_kernel(
    const float* __restrict__ ca_b_in, const float* __restrict__ ca_w_out,
    const float* __restrict__ ca_b_out, float* __restrict__ out)
{
    const int idx = blockIdx.x * 256 + threadIdx.x;
    const int l = idx >> 10;
    const int d = idx & 1023;
    const float* bv = ca_b_in + (size_t)l * 3 * D_ + 2 * D_;
    const float* w  = ca_w_out + (size_t)l * D_ * D_;
    float s = ca_b_out[(size_t)l * D_ + d];
    for (int k = 0; k < D_; ++k) s = fmaf(bv[k], w[(size_t)k * D_ + d], s);
    out[idx] = s;
}

// ---------------------------------------------------------------------------
extern "C" void kernel_launch(void* const* d_in, const int* in_sizes, int n_in,
                              void* d_out, int out_size, void* d_ws, size_t ws_size,
                              hipStream_t stream)
{
    const float* obs     = (const float*)d_in[0];
    const float* act     = (const float*)d_in[1];
    const float* in_w1   = (const float*)d_in[2];
    const float* in_b1   = (const float*)d_in[3];
    const float* in_w2   = (const float*)d_in[4];
    const float* in_b2   = (const float*)d_in[5];
    const float* in_w3   = (const float*)d_in[6];
    const float* in_b3   = (const float*)d_in[7];
    const float* act_w1  = (const float*)d_in[8];
    const float* act_b1  = (const float*)d_in[9];
    const float* act_w2  = (const float*)d_in[10];
    const float* act_b2  = (const float*)d_in[11];
    const float* act_w3  = (const float*)d_in[12];
    const float* act_b3  = (const float*)d_in[13];
    const float* out_w1  = (const float*)d_in[14];
    const float* out_b1  = (const float*)d_in[15];
    const float* out_w2  = (const float*)d_in[16];
    const float* out_b2  = (const float*)d_in[17];
    const float* out_w3  = (const float*)d_in[18];
    const float* out_b3  = (const float*)d_in[19];
    const float* sa_w_in = (const float*)d_in[20];
    const float* sa_b_in = (const float*)d_in[21];
    const float* sa_w_out= (const float*)d_in[22];
    const float* sa_b_out= (const float*)d_in[23];
    const float* ca_b_in = (const float*)d_in[25];
    const float* ca_w_out= (const float*)d_in[26];
    const float* ca_b_out= (const float*)d_in[27];
    const float* ff_w1   = (const float*)d_in[28];
    const float* ff_b1   = (const float*)d_in[29];
    const float* ff_w2   = (const float*)d_in[30];
    const float* ff_b2   = (const float*)d_in[31];
    const float* ln1_g   = (const float*)d_in[32];
    const float* ln1_b   = (const float*)d_in[33];
    const float* ln2_g   = (const float*)d_in[34];
    const float* ln2_b   = (const float*)d_in[35];
    const float* ln3_g   = (const float*)d_in[36];
    const float* ln3_b   = (const float*)d_in[37];
    const float* lnf_g   = (const float*)d_in[38];
    const float* lnf_b   = (const float*)d_in[39];

    const int MT = B_ * T_;          // 4092
    const int Mo = B_ * S_;          // 2048
    const int Ma = B_ * (S_ - 1);    // 2044

    // ---- workspace carve-up (256B aligned) ----
    char* base = (char*)d_ws;
    size_t used = 0;
    auto alloc = [&](size_t bytes) -> char* {
        char* r = base + used;
        used += (bytes + 255) & ~(size_t)255;
        return r;
    };
    typedef __hip_bfloat16 bf;
    bf* wi1  = (bf*)alloc((size_t)1024 * 64 * 2);
    bf* wi2  = (bf*)alloc((size_t)1024 * 1024 * 2);
    bf* wi3  = (bf*)alloc((size_t)1024 * 1024 * 2);
    bf* wa1  = (bf*)alloc((size_t)1024 * 32 * 2);
    bf* wa2  = (bf*)alloc((size_t)1024 * 1024 * 2);
    bf* wa3  = (bf*)alloc((size_t)1024 * 1024 * 2);
    bf* wo1  = (bf*)alloc((size_t)1024 * 1024 * 2);
    bf* wo2  = (bf*)alloc((size_t)1024 * 1024 * 2);
    bf* wo3  = (bf*)alloc((size_t)16 * 1024 * 2);
    bf* wsin = (bf*)alloc((size_t)L_ * 3072 * 1024 * 2);
    bf* wsout= (bf*)alloc((size_t)L_ * 1024 * 1024 * 2);
    bf* wf1  = (bf*)alloc((size_t)L_ * 4096 * 1024 * 2);
    bf* wf2  = (bf*)alloc((size_t)L_ * 1024 * 4096 * 2);
    bf* obs_bf = (bf*)alloc((size_t)Mo * 64 * 2);
    bf* act_bf = (bf*)alloc((size_t)Ma * 32 * 2);
    bf* x_bf   = (bf*)alloc((size_t)MT * D_ * 2);
    bf* attnb  = (bf*)alloc((size_t)MT * D_ * 2);
    bf* h1b    = (bf*)alloc((size_t)MT * D_ * 2);
    bf* h2b    = (bf*)alloc((size_t)MT * D_ * 2);
    float* x     = (float*)alloc((size_t)MT * D_ * 4);
    float* y     = (float*)alloc((size_t)MT * D_ * 4);
    float* qkv   = (float*)alloc((size_t)MT * 3 * D_ * 4);   // also reused as ffh (bf16) region
    float* obs_tok = (float*)alloc((size_t)Mo * D_ * 4);
    float* act_tok = (float*)alloc((size_t)Ma * D_ * 4);
    float* ca      = (float*)alloc((size_t)L_ * D_ * 4);
    bf* ffh = (bf*)qkv;  // alias: ffn hidden (bf16, 33.5MB) fits in qkv (50.3MB)
    if (used > ws_size) return;  // visible failure, no corruption

    auto tw = [&](const float* W, bf* Wt, int K, int N, int Kpad, int batch) {
        dim3 g((N + 31) / 32, (Kpad + 31) / 32, batch);
        transpose_w<<<g, 256, 0, stream>>>(W, Wt, K, N, Kpad);
    };
    auto gemm = [&](const bf* A, const bf* Wt, const float* bias,
                    float* Cf, bf* Cb, int M, int K, int N, int relu) {
        dim3 g((N + 127) / 128, (M + 127) / 128);
        gemm_bf16<<<g, 256, 0, stream>>>(A, Wt, bias, Cf, Cb, M, K, N, relu);
    };

    // ---- weight transpose+convert (every call; ~60us of BW) ----
    tw(in_w1,  wi1, 64,   1024, 64,   1);
    tw(in_w2,  wi2, 1024, 1024, 1024, 1);
    tw(in_w3,  wi3, 1024, 1024, 1024, 1);
    tw(act_w1, wa1, 16,   1024, 32,   1);   // K padded 16->32 with zeros
    tw(act_w2, wa2, 1024, 1024, 1024, 1);
    tw(act_w3, wa3, 1024, 1024, 1024, 1);
    tw(out_w1, wo1, 1024, 1024, 1024, 1);
    tw(out_w2, wo2, 1024, 1024, 1024, 1);
    tw(out_w3, wo3, 1024, 16,   1024, 1);
    tw(sa_w_in,  wsin,  1024, 3072, 1024, L_);
    tw(sa_w_out, wsout, 1024, 1024, 1024, L_);
    tw(ff_w1,    wf1,   1024, 4096, 1024, L_);
    tw(ff_w2,    wf2,   4096, 1024, 4096, L_);

    convert_pad<<<(Mo * 64 + 255) / 256, 256, 0, stream>>>(obs, obs_bf, Mo, 64, 64);
    convert_pad<<<(Ma * 32 + 255) / 256, 256, 0, stream>>>(act, act_bf, Ma, 16, 32);
    ca_const_kernel<<<(L_ * D_) / 256, 256, 0, stream>>>(ca_b_in, ca_w_out, ca_b_out, ca);

    // ---- input MLPs ----
    gemm(obs_bf, wi1, in_b1, nullptr, h1b, Mo, 64,   D_, 1);
    gemm(h1b,    wi2, in_b2, nullptr, h2b, Mo, D_,   D_, 1);
    gemm(h2b,    wi3, in_b3, obs_tok, nullptr, Mo, D_, D_, 0);
    gemm(act_bf, wa1, act_b1, nullptr, h1b, Ma, 32,  D_, 1);
    gemm(h1b,    wa2, act_b2, nullptr, h2b, Ma, D_,  D_, 1);
    gemm(h2b,    wa3, act_b3, act_tok, nullptr, Ma, D_, D_, 0);

    interleave_pe_kernel<<<MT, 256, 0, stream>>>(obs_tok, act_tok, x, x_bf);

    // ---- decoder layers ----
    for (int l = 0; l < L_; ++l) {
        gemm(x_bf, wsin + (size_t)l * 3072 * 1024, sa_b_in + (size_t)l * 3 * D_,
             qkv, nullptr, MT, D_, 3 * D_, 0);
        attn_kernel<<<dim3(B_ * H_, 8), 128, 0, stream>>>(qkv, attnb);
        gemm(attnb, wsout + (size_t)l * 1024 * 1024, sa_b_out + (size_t)l * D_,
             y, nullptr, MT, D_, D_, 0);
        add_ln_kernel<<<MT, 256, 0, stream>>>(x, y, 0,
             ln1_g + (size_t)l * D_, ln1_b + (size_t)l * D_, nullptr);
        add_ln_kernel<<<MT, 256, 0, stream>>>(x, ca + (size_t)l * D_, 1,
             ln2_g + (size_t)l * D_, ln2_b + (size_t)l * D_, x_bf);
        gemm(x_bf, wf1 + (size_t)l * 4096 * 1024, ff_b1 + (size_t)l * F_,
             nullptr, ffh, MT, D_, F_, 1);
        gemm(ffh, wf2 + (size_t)l * 1024 * 4096, ff_b2 + (size_t)l * D_,
             y, nullptr, MT, F_, D_, 0);
        add_ln_kernel<<<MT, 256, 0, stream>>>(x, y, 0,
             ln3_g + (size_t)l * D_, ln3_b + (size_t)l * D_, x_bf);
    }

    // ---- final norm + output MLP ----
    add_ln_kernel<<<MT, 256, 0, stream>>>(x, nullptr, 0, lnf_g, lnf_b, x_bf);
    gemm(x_bf, wo1, out_b1, nullptr, h1b, MT, D_, D_, 1);
    gemm(h1b,  wo2, out_b2, nullptr, h2b, MT, D_, D_, 1);
    gemm(h2b,  wo3, out_b3, (float*)d_out, nullptr, MT, D_, 16, 0);
}

// Round 3
// 1847.165 us; speedup vs baseline: 7.9635x; 3.0199x over previous
//
#include <hip/hip_runtime.h>
#include <hip/hip_bf16.h>
#include <cstdint>
#include <cstddef>

#define B_  4
#define S_  512
#define T_  1023
#define D_  1024
#define H_  16
#define DH_ 64
#define F_  4096
#define L_  4

typedef float f32x4 __attribute__((ext_vector_type(4)));
typedef __bf16 bf16x8 __attribute__((ext_vector_type(8)));

__device__ inline unsigned pack_bf2(float a, float b) {
    union { __hip_bfloat16 h; unsigned short u; } ua, ub;
    ua.h = __float2bfloat16(a); ub.h = __float2bfloat16(b);
    return (unsigned)ua.u | ((unsigned)ub.u << 16);
}

// ---------------------------------------------------------------------------
// bf16 MFMA GEMM (unchanged from round 2 — proven): C = op(A @ Wt^T + bias).
// ---------------------------------------------------------------------------
__global__ __launch_bounds__(256) void gemm_bf16(
    const __hip_bfloat16* __restrict__ A, const __hip_bfloat16* __restrict__ Wt,
    const float* __restrict__ bias,
    float* __restrict__ Cf, __hip_bfloat16* __restrict__ Cb,
    int M, int K, int N, int relu)
{
    __shared__ __align__(16) __hip_bfloat16 Asm[128 * 32];
    __shared__ __align__(16) __hip_bfloat16 Bsm[128 * 32];
    const int tid  = threadIdx.x;
    const int lane = tid & 63;
    const int w    = tid >> 6;
    const int wr   = w >> 1, wc = w & 1;
    const int l15  = lane & 15, l4 = lane >> 4;
    const int row0 = blockIdx.y * 128;
    const int col0 = blockIdx.x * 128;

    f32x4 acc[4][4] = {};

    auto* ldsA = (__attribute__((address_space(3))) char*)Asm;
    auto* ldsB = (__attribute__((address_space(3))) char*)Bsm;

    for (int kt = 0; kt < K; kt += 32) {
        #pragma unroll
        for (int half = 0; half < 2; ++half) {
            const int ch = half * 256 + w * 64 + lane;
            const int r  = ch >> 2;
            const int c  = (ch & 3) * 8;
            int gr = row0 + r; gr = (gr < M) ? gr : (M - 1);
            const __hip_bfloat16* srcA = A + (size_t)gr * K + kt + c;
            __builtin_amdgcn_global_load_lds(
                (const __attribute__((address_space(1))) unsigned*)srcA,
                (__attribute__((address_space(3))) unsigned*)(ldsA + (size_t)(half * 256 + w * 64) * 16),
                16, 0, 0);
            int gc = col0 + r; gc = (gc < N) ? gc : (N - 1);
            const __hip_bfloat16* srcB = Wt + (size_t)gc * K + kt + c;
            __builtin_amdgcn_global_load_lds(
                (const __attribute__((address_space(1))) unsigned*)srcB,
                (__attribute__((address_space(3))) unsigned*)(ldsB + (size_t)(half * 256 + w * 64) * 16),
                16, 0, 0);
        }
        __syncthreads();

        const __hip_bfloat16* ab = Asm + (size_t)(wr * 64 + l15) * 32 + l4 * 8;
        const __hip_bfloat16* bb = Bsm + (size_t)(wc * 64 + l15) * 32 + l4 * 8;
        bf16x8 af[4], bf[4];
        #pragma unroll
        for (int mi = 0; mi < 4; ++mi) af[mi] = *(const bf16x8*)(ab + mi * 16 * 32);
        #pragma unroll
        for (int nj = 0; nj < 4; ++nj) bf[nj] = *(const bf16x8*)(bb + nj * 16 * 32);
        #pragma unroll
        for (int mi = 0; mi < 4; ++mi)
            #pragma unroll
            for (int nj = 0; nj < 4; ++nj)
                acc[mi][nj] = __builtin_amdgcn_mfma_f32_16x16x32_bf16(
                    af[mi], bf[nj], acc[mi][nj], 0, 0, 0);
        __syncthreads();
    }

    #pragma unroll
    for (int nj = 0; nj < 4; ++nj) {
        const int c = col0 + wc * 64 + nj * 16 + l15;
        if (c >= N) continue;
        const float bv = bias[c];
        #pragma unroll
        for (int mi = 0; mi < 4; ++mi) {
            #pragma unroll
            for (int i = 0; i < 4; ++i) {
                const int r = row0 + wr * 64 + mi * 16 + l4 * 4 + i;
                if (r >= M) continue;
                float v = acc[mi][nj][i] + bv;
                if (relu) v = fmaxf(v, 0.f);
                if (Cf) Cf[(size_t)r * N + c] = v;
                if (Cb) Cb[(size_t)r * N + c] = __float2bfloat16(v);
            }
        }
    }
}

// ---------------------------------------------------------------------------
// Weight transpose+convert (unchanged).
// ---------------------------------------------------------------------------
__global__ __launch_bounds__(256) void transpose_w(
    const float* __restrict__ W, __hip_bfloat16* __restrict__ Wt,
    int K, int N, int Kpad)
{
    __shared__ float t[32][33];
    W  += (size_t)blockIdx.z * K * N;
    Wt += (size_t)blockIdx.z * N * Kpad;
    const int n0 = blockIdx.x * 32, k0 = blockIdx.y * 32;
    const int tx = threadIdx.x & 31, ty = threadIdx.x >> 5;
    #pragma unroll
    for (int i = 0; i < 4; ++i) {
        int r = ty + i * 8;
        int k = k0 + r, n = n0 + tx;
        t[r][tx] = (k < K && n < N) ? W[(size_t)k * N + n] : 0.f;
    }
    __syncthreads();
    #pragma unroll
    for (int i = 0; i < 4; ++i) {
        int r = ty + i * 8;
        int n = n0 + r, k = k0 + tx;
        if (n < N && k < Kpad) Wt[(size_t)n * Kpad + k] = __float2bfloat16(t[tx][r]);
    }
}

__global__ __launch_bounds__(256) void convert_pad(
    const float* __restrict__ in, __hip_bfloat16* __restrict__ out,
    int M, int Kin, int Kout)
{
    int idx = blockIdx.x * 256 + threadIdx.x;
    if (idx >= M * Kout) return;
    int r = idx / Kout, c = idx - r * Kout;
    out[idx] = __float2bfloat16(c < Kin ? in[(size_t)r * Kin + c] : 0.f);
}

// ---------------------------------------------------------------------------
// V transpose (bf16): vt[b][c][t] = qkvb[b*T+t][2048+c]. Pad t=1023 -> 0.
// grid (32 c-tiles, 32 t-tiles, B), block 256.
// ---------------------------------------------------------------------------
__global__ __launch_bounds__(256) void v_transpose(
    const __hip_bfloat16* __restrict__ qkvb, __hip_bfloat16* __restrict__ vt)
{
    __shared__ __hip_bfloat16 tile[32][33];
    const int b  = blockIdx.z;
    const int c0 = blockIdx.x * 32;
    const int t0 = blockIdx.y * 32;
    const int tx = threadIdx.x & 31, ty = threadIdx.x >> 5;
    const __hip_bfloat16 z = __float2bfloat16(0.f);
    #pragma unroll
    for (int i = 0; i < 4; ++i) {
        const int tl = ty + i * 8;
        const int t = t0 + tl;
        tile[tl][tx] = (t < T_) ? qkvb[(size_t)(b * T_ + t) * 3072 + 2048 + c0 + tx] : z;
    }
    __syncthreads();
    #pragma unroll
    for (int i = 0; i < 4; ++i) {
        const int cl = ty + i * 8;
        const int t = t0 + tx;
        vt[((size_t)(b * 1024 + c0 + cl)) * 1024 + t] = (t < T_) ? tile[tx][cl] : z;
    }
}

// ---------------------------------------------------------------------------
// MFMA flash attention (causal, no-max softmax — scores O(0.4) for this net).
// qkvb: [B*T][3072] bf16 (Q|K|V).  vt: [B][1024][1024] bf16 (V^T per b).
// out:  [B*T][1024] bf16.
// grid (B*H=64, T/128=8), block 256 = 4 waves; wave w owns q rows w*32..+31.
// Fragment conventions identical to gemm_bf16 (A row=lane&15, k=(lane>>4)*8;
// C: row=(lane>>4)*4+i, col=lane&15).
// ---------------------------------------------------------------------------
__global__ __launch_bounds__(256) void attn_mfma(
    const __hip_bfloat16* __restrict__ qkvb,
    const __hip_bfloat16* __restrict__ vt,
    __hip_bfloat16* __restrict__ out)
{
    __shared__ __align__(16) __hip_bfloat16 Qs[2][128][32];   // 16 KB
    __shared__ __align__(16) __hip_bfloat16 Ks[2][64][32];    // 8 KB
    __shared__ __align__(16) __hip_bfloat16 Vs[2][64][32];    // 8 KB (V^T tile)
    __shared__ __align__(16) __hip_bfloat16 Ps[4][2][32][32]; // 16 KB wave-private P
    __shared__ float Lw[4][2][16];

    const int bh = blockIdx.x;
    const int b = bh >> 4, h = bh & 15;
    const int q0 = blockIdx.y * 128;
    const int tid = threadIdx.x;
    const int w = tid >> 6, lane = tid & 63;
    const int l15 = lane & 15, l4 = lane >> 4;
    const size_t ldq = 3 * D_;

    // ---- stage Q tile [128][64] as two 32-d chunks ----
    {
        #pragma unroll
        for (int c = 0; c < 2; ++c)
            #pragma unroll
            for (int it = 0; it < 2; ++it) {
                const int ch = it * 256 + tid;             // 512 chunks of 16B
                const int r = ch >> 2, cp = ch & 3;
                int qr = q0 + r; qr = (qr < T_) ? qr : (T_ - 1);
                const __hip_bfloat16* src = qkvb + (size_t)(b * T_ + qr) * ldq + h * 64 + c * 32 + cp * 8;
                __builtin_amdgcn_global_load_lds(
                    (const __attribute__((address_space(1))) unsigned*)src,
                    (__attribute__((address_space(3))) unsigned*)((__attribute__((address_space(3))) char*)&Qs[c][0][0] + ch * 16),
                    16, 0, 0);
            }
    }
    __syncthreads();
    bf16x8 qreg[2][2];
    #pragma unroll
    for (int qf = 0; qf < 2; ++qf)
        #pragma unroll
        for (int c = 0; c < 2; ++c)
            qreg[qf][c] = *(const bf16x8*)&Qs[c][w * 32 + qf * 16 + l15][l4 * 8];

    f32x4 of[2][4] = {};
    float lp[2] = {0.f, 0.f};
    const int qmaxw = q0 + w * 32 + 31;
    const int kend = (q0 + 128 < T_) ? (q0 + 128) : T_;

    for (int k0 = 0; k0 < kend; k0 += 64) {
        __syncthreads();                       // protect K/V from overwrite
        {
            const int r = tid >> 2, cp = tid & 3;   // 256 chunks per buffer
            #pragma unroll
            for (int c = 0; c < 2; ++c) {
                int kr = k0 + r; kr = (kr < T_) ? kr : (T_ - 1);
                const __hip_bfloat16* srcK = qkvb + (size_t)(b * T_ + kr) * ldq + D_ + h * 64 + c * 32 + cp * 8;
                __builtin_amdgcn_global_load_lds(
                    (const __attribute__((address_space(1))) unsigned*)srcK,
                    (__attribute__((address_space(3))) unsigned*)((__attribute__((address_space(3))) char*)&Ks[c][0][0] + tid * 16),
                    16, 0, 0);
                const __hip_bfloat16* srcV = vt + ((size_t)(b * 1024 + h * 64 + r)) * 1024 + k0 + c * 32 + cp * 8;
                __builtin_amdgcn_global_load_lds(
                    (const __attribute__((address_space(1))) unsigned*)srcV,
                    (__attribute__((address_space(3))) unsigned*)((__attribute__((address_space(3))) char*)&Vs[c][0][0] + tid * 16),
                    16, 0, 0);
            }
        }
        __syncthreads();

        if (k0 <= qmaxw) {
            // ---- QK^T: S[k=row, q=col] fragments ----
            f32x4 sf[4][2] = {};
            #pragma unroll
            for (int c = 0; c < 2; ++c) {
                bf16x8 kf[4];
                #pragma unroll
                for (int kfr = 0; kfr < 4; ++kfr)
                    kf[kfr] = *(const bf16x8*)&Ks[c][kfr * 16 + l15][l4 * 8];
                #pragma unroll
                for (int kfr = 0; kfr < 4; ++kfr)
                    #pragma unroll
                    for (int qf = 0; qf < 2; ++qf)
                        sf[kfr][qf] = __builtin_amdgcn_mfma_f32_16x16x32_bf16(
                            kf[kfr], qreg[qf][c], sf[kfr][qf], 0, 0, 0);
            }
            // ---- softmax (no max-tracking) + P -> LDS ----
            const bool needmask = (k0 + 63) > (q0 + w * 32);
            #pragma unroll
            for (int kfr = 0; kfr < 4; ++kfr) {
                #pragma unroll
                for (int qf = 0; qf < 2; ++qf) {
                    const int qg = q0 + w * 32 + qf * 16 + l15;
                    float p[4];
                    #pragma unroll
                    for (int i = 0; i < 4; ++i) {
                        const int kg = k0 + kfr * 16 + l4 * 4 + i;
                        float pv = __expf(sf[kfr][qf][i] * 0.125f);
                        if (needmask && kg > qg) pv = 0.f;
                        p[i] = pv;
                        lp[qf] += pv;
                    }
                    unsigned* dst = (unsigned*)&Ps[w][kfr >> 1][qf * 16 + l15][(kfr & 1) * 16 + l4 * 4];
                    dst[0] = pack_bf2(p[0], p[1]);
                    dst[1] = pack_bf2(p[2], p[3]);
                }
            }
            // ---- PV: O[q=row, d=col] += P-frag x V^T-frag ----
            #pragma unroll
            for (int kc = 0; kc < 2; ++kc) {
                bf16x8 pa[2], vb[4];
                #pragma unroll
                for (int qf = 0; qf < 2; ++qf)
                    pa[qf] = *(const bf16x8*)&Ps[w][kc][qf * 16 + l15][l4 * 8];
                #pragma unroll
                for (int df = 0; df < 4; ++df)
                    vb[df] = *(const bf16x8*)&Vs[kc][df * 16 + l15][l4 * 8];
                #pragma unroll
                for (int qf = 0; qf < 2; ++qf)
                    #pragma unroll
                    for (int df = 0; df < 4; ++df)
                        of[qf][df] = __builtin_amdgcn_mfma_f32_16x16x32_bf16(
                            pa[qf], vb[df], of[qf][df], 0, 0, 0);
            }
        }
    }

    // ---- deferred l reduction across l4 groups, redistribute via LDS ----
    #pragma unroll
    for (int qf = 0; qf < 2; ++qf) {
        float v = lp[qf];
        v += __shfl_xor(v, 16);
        v += __shfl_xor(v, 32);
        if (l4 == 0) Lw[w][qf][l15] = v;
    }
    __syncthreads();   // cheap; guarantees Lw visible (wave-private but be safe)
    #pragma unroll
    for (int qf = 0; qf < 2; ++qf) {
        float inv[4];
        #pragma unroll
        for (int i = 0; i < 4; ++i) inv[i] = 1.f / Lw[w][qf][l4 * 4 + i];
        #pragma unroll
        for (int df = 0; df < 4; ++df) {
            #pragma unroll
            for (int i = 0; i < 4; ++i) {
                const int qg = q0 + w * 32 + qf * 16 + l4 * 4 + i;
                if (qg < T_)
                    out[(size_t)(b * T_ + qg) * D_ + h * 64 + df * 16 + l15] =
                        __float2bfloat16(of[qf][df][i] * inv[i]);
            }
        }
    }
}

// ---------------------------------------------------------------------------
// add + LN (unchanged).
// ---------------------------------------------------------------------------
__global__ __launch_bounds__(256) void add_ln_kernel(
    float* __restrict__ x, const float* __restrict__ y, int ybcast,
    const float* __restrict__ g, const float* __restrict__ beta,
    __hip_bfloat16* __restrict__ xb)
{
    const int row = blockIdx.x;
    const int tid = threadIdx.x;
    float4* xr = reinterpret_cast<float4*>(x + (size_t)row * D_);
    float4 v = xr[tid];
    if (y) {
        const float4* yr = reinterpret_cast<const float4*>(
            ybcast ? y : y + (size_t)row * D_);
        float4 wv = yr[tid];
        v.x += wv.x; v.y += wv.y; v.z += wv.z; v.w += wv.w;
    }
    float s  = v.x + v.y + v.z + v.w;
    float s2 = v.x * v.x + v.y * v.y + v.z * v.z + v.w * v.w;
    #pragma unroll
    for (int off = 32; off; off >>= 1) {
        s  += __shfl_down(s, off);
        s2 += __shfl_down(s2, off);
    }
    __shared__ float ws[4], ws2[4];
    __shared__ float mu_s, inv_s;
    const int wid = tid >> 6;
    if ((tid & 63) == 0) { ws[wid] = s; ws2[wid] = s2; }
    __syncthreads();
    if (tid == 0) {
        float S  = ws[0] + ws[1] + ws[2] + ws[3];
        float S2 = ws2[0] + ws2[1] + ws2[2] + ws2[3];
        float mu = S * (1.f / (float)D_);
        float var = S2 * (1.f / (float)D_) - mu * mu;
        mu_s = mu;
        inv_s = rsqrtf(var + 1e-5f);
    }
    __syncthreads();
    const float mu = mu_s, inv = inv_s;
    const float4 gg = reinterpret_cast<const float4*>(g)[tid];
    const float4 bb = reinterpret_cast<const float4*>(beta)[tid];
    float4 o;
    o.x = (v.x - mu) * inv * gg.x + bb.x;
    o.y = (v.y - mu) * inv * gg.y + bb.y;
    o.z = (v.z - mu) * inv * gg.z + bb.z;
    o.w = (v.w - mu) * inv * gg.w + bb.w;
    xr[tid] = o;
    if (xb) {
        __hip_bfloat16* xo = xb + (size_t)row * D_ + tid * 4;
        xo[0] = __float2bfloat16(o.x);
        xo[1] = __float2bfloat16(o.y);
        xo[2] = __float2bfloat16(o.z);
        xo[3] = __float2bfloat16(o.w);
    }
}

__global__ __launch_bounds__(256) void interleave_pe_kernel(
    const float* __restrict__ obs_tok, const float* __restrict__ act_tok,
    float* __restrict__ x, __hip_bfloat16* __restrict__ xb)
{
    const int row = blockIdx.x;
    const int b = row / T_;
    const int t = row - b * T_;
    const float* src = (t & 1)
        ? (act_tok + (size_t)(b * (S_ - 1) + (t >> 1)) * D_)
        : (obs_tok + (size_t)(b * S_ + (t >> 1)) * D_);
    float* xr = x + (size_t)row * D_;
    __hip_bfloat16* xo = xb + (size_t)row * D_;
    #pragma unroll
    for (int k = 0; k < 4; ++k) {
        int d = threadIdx.x + k * 256;
        float ang = (float)b * expf(-(float)(d & ~1) * (9.210340371976184f / 1024.0f));
        float pe = (d & 1) ? cosf(ang) : sinf(ang);
        float v = src[d] + pe;
        xr[d] = v;
        xo[d] = __float2bfloat16(v);
    }
}

__global__ __launch_bounds__(256) void ca_const_kernel(
    const float* __restrict__ ca_b_in, const float* __restrict__ ca_w_out,
    const float* __restrict__ ca_b_out, float* __restrict__ out)
{
    const int idx = blockIdx.x * 256 + threadIdx.x;
    const int l = idx >> 10;
    const int d = idx & 1023;
    const float* bv = ca_b_in + (size_t)l * 3 * D_ + 2 * D_;
    const float* w  = ca_w_out + (size_t)l * D_ * D_;
    float s = ca_b_out[(size_t)l * D_ + d];
    for (int k = 0; k < D_; ++k) s = fmaf(bv[k], w[(size_t)k * D_ + d], s);
    out[idx] = s;
}

// ---------------------------------------------------------------------------
extern "C" void kernel_launch(void* const* d_in, const int* in_sizes, int n_in,
                              void* d_out, int out_size, void* d_ws, size_t ws_size,
                              hipStream_t stream)
{
    const float* obs     = (const float*)d_in[0];
    const float* act     = (const float*)d_in[1];
    const float* in_w1   = (const float*)d_in[2];
    const float* in_b1   = (const float*)d_in[3];
    const float* in_w2   = (const float*)d_in[4];
    const float* in_b2   = (const float*)d_in[5];
    const float* in_w3   = (const float*)d_in[6];
    const float* in_b3   = (const float*)d_in[7];
    const float* act_w1  = (const float*)d_in[8];
    const float* act_b1  = (const float*)d_in[9];
    const float* act_w2  = (const float*)d_in[10];
    const float* act_b2  = (const float*)d_in[11];
    const float* act_w3  = (const float*)d_in[12];
    const float* act_b3  = (const float*)d_in[13];
    const float* out_w1  = (const float*)d_in[14];
    const float* out_b1  = (const float*)d_in[15];
    const float* out_w2  = (const float*)d_in[16];
    const float* out_b2  = (const float*)d_in[17];
    const float* out_w3  = (const float*)d_in[18];
    const float* out_b3  = (const float*)d_in[19];
    const float* sa_w_in = (const float*)d_in[20];
    const float* sa_b_in = (const float*)d_in[21];
    const float* sa_w_out= (const float*)d_in[22];
    const float* sa_b_out= (const float*)d_in[23];
    const float* ca_b_in = (const float*)d_in[25];
    const float* ca_w_out= (const float*)d_in[26];
    const float* ca_b_out= (const float*)d_in[27];
    const float* ff_w1   = (const float*)d_in[28];
    const float* ff_b1   = (const float*)d_in[29];
    const float* ff_w2   = (const float*)d_in[30];
    const float* ff_b2   = (const float*)d_in[31];
    const float* ln1_g   = (const float*)d_in[32];
    const float* ln1_b   = (const float*)d_in[33];
    const float* ln2_g   = (const float*)d_in[34];
    const float* ln2_b   = (const float*)d_in[35];
    const float* ln3_g   = (const float*)d_in[36];
    const float* ln3_b   = (const float*)d_in[37];
    const float* lnf_g   = (const float*)d_in[38];
    const float* lnf_b   = (const float*)d_in[39];

    const int MT = B_ * T_;          // 4092
    const int Mo = B_ * S_;          // 2048
    const int Ma = B_ * (S_ - 1);    // 2044

    char* base = (char*)d_ws;
    size_t used = 0;
    auto alloc = [&](size_t bytes) -> char* {
        char* r = base + used;
        used += (bytes + 255) & ~(size_t)255;
        return r;
    };
    typedef __hip_bfloat16 bf;
    bf* wi1  = (bf*)alloc((size_t)1024 * 64 * 2);
    bf* wi2  = (bf*)alloc((size_t)1024 * 1024 * 2);
    bf* wi3  = (bf*)alloc((size_t)1024 * 1024 * 2);
    bf* wa1  = (bf*)alloc((size_t)1024 * 32 * 2);
    bf* wa2  = (bf*)alloc((size_t)1024 * 1024 * 2);
    bf* wa3  = (bf*)alloc((size_t)1024 * 1024 * 2);
    bf* wo1  = (bf*)alloc((size_t)1024 * 1024 * 2);
    bf* wo2  = (bf*)alloc((size_t)1024 * 1024 * 2);
    bf* wo3  = (bf*)alloc((size_t)16 * 1024 * 2);
    bf* wsin = (bf*)alloc((size_t)L_ * 3072 * 1024 * 2);
    bf* wsout= (bf*)alloc((size_t)L_ * 1024 * 1024 * 2);
    bf* wf1  = (bf*)alloc((size_t)L_ * 4096 * 1024 * 2);
    bf* wf2  = (bf*)alloc((size_t)L_ * 1024 * 4096 * 2);
    bf* obs_bf = (bf*)alloc((size_t)Mo * 64 * 2);
    bf* act_bf = (bf*)alloc((size_t)Ma * 32 * 2);
    bf* x_bf   = (bf*)alloc((size_t)MT * D_ * 2);
    bf* attnb  = (bf*)alloc((size_t)MT * D_ * 2);
    bf* h1b    = (bf*)alloc((size_t)MT * D_ * 2);
    bf* h2b    = (bf*)alloc((size_t)MT * D_ * 2);
    // shared region: qkvb [MT][3072] bf16 (25.1MB) | ffh [MT][4096] bf16 (33.5MB)
    char* shared_rg = alloc((size_t)MT * F_ * 2);
    bf* qkvb = (bf*)shared_rg;
    bf* ffh  = (bf*)shared_rg;
    bf* vt   = (bf*)alloc((size_t)B_ * 1024 * 1024 * 2);   // V^T, 8.4MB
    float* x       = (float*)alloc((size_t)MT * D_ * 4);
    float* y       = (float*)alloc((size_t)MT * D_ * 4);
    float* obs_tok = (float*)alloc((size_t)Mo * D_ * 4);
    float* act_tok = (float*)alloc((size_t)Ma * D_ * 4);
    float* ca      = (float*)alloc((size_t)L_ * D_ * 4);
    if (used > ws_size) return;  // visible failure, no corruption

    auto tw = [&](const float* W, bf* Wt, int K, int N, int Kpad, int batch) {
        dim3 g((N + 31) / 32, (Kpad + 31) / 32, batch);
        transpose_w<<<g, 256, 0, stream>>>(W, Wt, K, N, Kpad);
    };
    auto gemm = [&](const bf* A, const bf* Wt, const float* bias,
                    float* Cf, bf* Cb, int M, int K, int N, int relu) {
        dim3 g((N + 127) / 128, (M + 127) / 128);
        gemm_bf16<<<g, 256, 0, stream>>>(A, Wt, bias, Cf, Cb, M, K, N, relu);
    };

    tw(in_w1,  wi1, 64,   1024, 64,   1);
    tw(in_w2,  wi2, 1024, 1024, 1024, 1);
    tw(in_w3,  wi3, 1024, 1024, 1024, 1);
    tw(act_w1, wa1, 16,   1024, 32,   1);
    tw(act_w2, wa2, 1024, 1024, 1024, 1);
    tw(act_w3, wa3, 1024, 1024, 1024, 1);
    tw(out_w1, wo1, 1024, 1024, 1024, 1);
    tw(out_w2, wo2, 1024, 1024, 1024, 1);
    tw(out_w3, wo3, 1024, 16,   1024, 1);
    tw(sa_w_in,  wsin,  1024, 3072, 1024, L_);
    tw(sa_w_out, wsout, 1024, 1024, 1024, L_);
    tw(ff_w1,    wf1,   1024, 4096, 1024, L_);
    tw(ff_w2,    wf2,   4096, 1024, 4096, L_);

    convert_pad<<<(Mo * 64 + 255) / 256, 256, 0, stream>>>(obs, obs_bf, Mo, 64, 64);
    convert_pad<<<(Ma * 32 + 255) / 256, 256, 0, stream>>>(act, act_bf, Ma, 16, 32);
    ca_const_kernel<<<(L_ * D_) / 256, 256, 0, stream>>>(ca_b_in, ca_w_out, ca_b_out, ca);

    // ---- input MLPs ----
    gemm(obs_bf, wi1, in_b1, nullptr, h1b, Mo, 64,   D_, 1);
    gemm(h1b,    wi2, in_b2, nullptr, h2b, Mo, D_,   D_, 1);
    gemm(h2b,    wi3, in_b3, obs_tok, nullptr, Mo, D_, D_, 0);
    gemm(act_bf, wa1, act_b1, nullptr, h1b, Ma, 32,  D_, 1);
    gemm(h1b,    wa2, act_b2, nullptr, h2b, Ma, D_,  D_, 1);
    gemm(h2b,    wa3, act_b3, act_tok, nullptr, Ma, D_, D_, 0);

    interleave_pe_kernel<<<MT, 256, 0, stream>>>(obs_tok, act_tok, x, x_bf);

    // ---- decoder layers ----
    for (int l = 0; l < L_; ++l) {
        gemm(x_bf, wsin + (size_t)l * 3072 * 1024, sa_b_in + (size_t)l * 3 * D_,
             nullptr, qkvb, MT, D_, 3 * D_, 0);
        v_transpose<<<dim3(32, 32, B_), 256, 0, stream>>>(qkvb, vt);
        attn_mfma<<<dim3(B_ * H_, 8), 256, 0, stream>>>(qkvb, vt, attnb);
        gemm(attnb, wsout + (size_t)l * 1024 * 1024, sa_b_out + (size_t)l * D_,
             y, nullptr, MT, D_, D_, 0);
        add_ln_kernel<<<MT, 256, 0, stream>>>(x, y, 0,
             ln1_g + (size_t)l * D_, ln1_b + (size_t)l * D_, nullptr);
        add_ln_kernel<<<MT, 256, 0, stream>>>(x, ca + (size_t)l * D_, 1,
             ln2_g + (size_t)l * D_, ln2_b + (size_t)l * D_, x_bf);
        gemm(x_bf, wf1 + (size_t)l * 4096 * 1024, ff_b1 + (size_t)l * F_,
             nullptr, ffh, MT, D_, F_, 1);
        gemm(ffh, wf2 + (size_t)l * 1024 * 4096, ff_b2 + (size_t)l * D_,
             y, nullptr, MT, F_, D_, 0);
        add_ln_kernel<<<MT, 256, 0, stream>>>(x, y, 0,
             ln3_g + (size_t)l * D_, ln3_b + (size_t)l * D_, x_bf);
    }

    // ---- final norm + output MLP ----
    add_ln_kernel<<<MT, 256, 0, stream>>>(x, nullptr, 0, lnf_g, lnf_b, x_bf);
    gemm(x_bf, wo1, out_b1, nullptr, h1b, MT, D_, D_, 1);
    gemm(h1b,  wo2, out_b2, nullptr, h2b, MT, D_, D_, 1);
    gemm(h2b,  wo3, out_b3, (float*)d_out, nullptr, MT, D_, 16, 0);
}

// Round 4
// 1688.961 us; speedup vs baseline: 8.7094x; 1.0937x over previous
//
#include <hip/hip_runtime.h>
#include <hip/hip_bf16.h>
#include <cstdint>
#include <cstddef>

#define B_  4
#define S_  512
#define T_  1023
#define D_  1024
#define H_  16
#define DH_ 64
#define F_  4096
#define L_  4

typedef float f32x4 __attribute__((ext_vector_type(4)));
typedef __bf16 bf16x8 __attribute__((ext_vector_type(8)));

__device__ inline unsigned pack_bf2(float a, float b) {
    union { __hip_bfloat16 h; unsigned short u; } ua, ub;
    ua.h = __float2bfloat16(a); ub.h = __float2bfloat16(b);
    return (unsigned)ua.u | ((unsigned)ub.u << 16);
}

// ---------------------------------------------------------------------------
// bf16 MFMA GEMM, 2-phase prefetch double-buffer (T3-min), XCD-swizzled grid.
// C[M,N] = op(A[M,K] @ Wt[N,K]^T + bias). Static LDS buffers (alias-safe).
// 128x128 tile, BK=32, 256 thr = 4 waves (2x2), wave = 64x64 via 4x4 MFMA.
// ---------------------------------------------------------------------------
__global__ __launch_bounds__(256) void gemm_bf16(
    const __hip_bfloat16* __restrict__ A, const __hip_bfloat16* __restrict__ Wt,
    const float* __restrict__ bias,
    float* __restrict__ Cf, __hip_bfloat16* __restrict__ Cb,
    int M, int K, int N, int relu)
{
    __shared__ __align__(16) __hip_bfloat16 Asm0[128 * 32];
    __shared__ __align__(16) __hip_bfloat16 Bsm0[128 * 32];
    __shared__ __align__(16) __hip_bfloat16 Asm1[128 * 32];
    __shared__ __align__(16) __hip_bfloat16 Bsm1[128 * 32];
    const int tid  = threadIdx.x;
    const int lane = tid & 63;
    const int w    = tid >> 6;
    const int wr   = w >> 1, wc = w & 1;
    const int l15  = lane & 15, l4 = lane >> 4;

    // bijective XCD-aware swizzle (m204): each XCD gets a contiguous tile chunk
    const int gx = gridDim.x;
    int bid = blockIdx.y * gx + blockIdx.x;
    {
        const int nwg = gx * gridDim.y;
        const int q = nwg >> 3, r = nwg & 7;
        const int xcd = bid & 7, idx = bid >> 3;
        bid = (xcd < r ? xcd * (q + 1) : r * (q + 1) + (xcd - r) * q) + idx;
    }
    const int row0 = (bid / gx) * 128;
    const int col0 = (bid % gx) * 128;

    f32x4 acc[4][4] = {};

    auto stage = [&](__hip_bfloat16* As, __hip_bfloat16* Bs, int kt) {
        auto* ldsA = (__attribute__((address_space(3))) char*)As;
        auto* ldsB = (__attribute__((address_space(3))) char*)Bs;
        #pragma unroll
        for (int half = 0; half < 2; ++half) {
            const int ch = half * 256 + tid;            // 16B chunk id
            const int r  = ch >> 2;
            const int c  = (ch & 3) * 8;
            int gr = row0 + r; gr = (gr < M) ? gr : (M - 1);
            const __hip_bfloat16* srcA = A + (size_t)gr * K + kt + c;
            __builtin_amdgcn_global_load_lds(
                (const __attribute__((address_space(1))) unsigned*)srcA,
                (__attribute__((address_space(3))) unsigned*)(ldsA + (size_t)ch * 16),
                16, 0, 0);
            int gc = col0 + r; gc = (gc < N) ? gc : (N - 1);
            const __hip_bfloat16* srcB = Wt + (size_t)gc * K + kt + c;
            __builtin_amdgcn_global_load_lds(
                (const __attribute__((address_space(1))) unsigned*)srcB,
                (__attribute__((address_space(3))) unsigned*)(ldsB + (size_t)ch * 16),
                16, 0, 0);
        }
    };
    auto compute = [&](const __hip_bfloat16* As, const __hip_bfloat16* Bs) {
        const __hip_bfloat16* ab = As + (size_t)(wr * 64 + l15) * 32 + l4 * 8;
        const __hip_bfloat16* bb = Bs + (size_t)(wc * 64 + l15) * 32 + l4 * 8;
        bf16x8 af[4], bf[4];
        #pragma unroll
        for (int mi = 0; mi < 4; ++mi) af[mi] = *(const bf16x8*)(ab + mi * 16 * 32);
        #pragma unroll
        for (int nj = 0; nj < 4; ++nj) bf[nj] = *(const bf16x8*)(bb + nj * 16 * 32);
        #pragma unroll
        for (int mi = 0; mi < 4; ++mi)
            #pragma unroll
            for (int nj = 0; nj < 4; ++nj)
                acc[mi][nj] = __builtin_amdgcn_mfma_f32_16x16x32_bf16(
                    af[mi], bf[nj], acc[mi][nj], 0, 0, 0);
    };

    const int nk = K >> 5;
    stage(Asm0, Bsm0, 0);
    __syncthreads();
    for (int t = 0; t < nk; t += 2) {
        if (t + 1 < nk) stage(Asm1, Bsm1, (t + 1) * 32);   // prefetch overlaps:
        compute(Asm0, Bsm0);                               //   ds_read + MFMA
        __syncthreads();                                   // drains vm+lgkm
        if (t + 1 < nk) {
            if (t + 2 < nk) stage(Asm0, Bsm0, (t + 2) * 32);
            compute(Asm1, Bsm1);
            __syncthreads();
        }
    }

    // epilogue: C/D layout col = lane&15, row = (lane>>4)*4 + i  [m89-verified]
    #pragma unroll
    for (int nj = 0; nj < 4; ++nj) {
        const int c = col0 + wc * 64 + nj * 16 + l15;
        if (c >= N) continue;
        const float bv = bias[c];
        #pragma unroll
        for (int mi = 0; mi < 4; ++mi) {
            #pragma unroll
            for (int i = 0; i < 4; ++i) {
                const int r = row0 + wr * 64 + mi * 16 + l4 * 4 + i;
                if (r >= M) continue;
                float v = acc[mi][nj][i] + bv;
                if (relu) v = fmaxf(v, 0.f);
                if (Cf) Cf[(size_t)r * N + c] = v;
                if (Cb) Cb[(size_t)r * N + c] = __float2bfloat16(v);
            }
        }
    }
}

// ---------------------------------------------------------------------------
// Weight transpose+convert (unchanged).
// ---------------------------------------------------------------------------
__global__ __launch_bounds__(256) void transpose_w(
    const float* __restrict__ W, __hip_bfloat16* __restrict__ Wt,
    int K, int N, int Kpad)
{
    __shared__ float t[32][33];
    W  += (size_t)blockIdx.z * K * N;
    Wt += (size_t)blockIdx.z * N * Kpad;
    const int n0 = blockIdx.x * 32, k0 = blockIdx.y * 32;
    const int tx = threadIdx.x & 31, ty = threadIdx.x >> 5;
    #pragma unroll
    for (int i = 0; i < 4; ++i) {
        int r = ty + i * 8;
        int k = k0 + r, n = n0 + tx;
        t[r][tx] = (k < K && n < N) ? W[(size_t)k * N + n] : 0.f;
    }
    __syncthreads();
    #pragma unroll
    for (int i = 0; i < 4; ++i) {
        int r = ty + i * 8;
        int n = n0 + r, k = k0 + tx;
        if (n < N && k < Kpad) Wt[(size_t)n * Kpad + k] = __float2bfloat16(t[tx][r]);
    }
}

__global__ __launch_bounds__(256) void convert_pad(
    const float* __restrict__ in, __hip_bfloat16* __restrict__ out,
    int M, int Kin, int Kout)
{
    int idx = blockIdx.x * 256 + threadIdx.x;
    if (idx >= M * Kout) return;
    int r = idx / Kout, c = idx - r * Kout;
    out[idx] = __float2bfloat16(c < Kin ? in[(size_t)r * Kin + c] : 0.f);
}

// ---------------------------------------------------------------------------
// V transpose (unchanged): vt[b][c][t] = qkvb[b*T+t][2048+c], pad t>=T -> 0.
// ---------------------------------------------------------------------------
__global__ __launch_bounds__(256) void v_transpose(
    const __hip_bfloat16* __restrict__ qkvb, __hip_bfloat16* __restrict__ vt)
{
    __shared__ __hip_bfloat16 tile[32][33];
    const int b  = blockIdx.z;
    const int c0 = blockIdx.x * 32;
    const int t0 = blockIdx.y * 32;
    const int tx = threadIdx.x & 31, ty = threadIdx.x >> 5;
    const __hip_bfloat16 z = __float2bfloat16(0.f);
    #pragma unroll
    for (int i = 0; i < 4; ++i) {
        const int tl = ty + i * 8;
        const int t = t0 + tl;
        tile[tl][tx] = (t < T_) ? qkvb[(size_t)(b * T_ + t) * 3072 + 2048 + c0 + tx] : z;
    }
    __syncthreads();
    #pragma unroll
    for (int i = 0; i < 4; ++i) {
        const int cl = ty + i * 8;
        const int t = t0 + tx;
        vt[((size_t)(b * 1024 + c0 + cl)) * 1024 + t] = (t < T_) ? tile[tx][cl] : z;
    }
}

// ---------------------------------------------------------------------------
// MFMA flash attention (unchanged from round 3 — proven).
// ---------------------------------------------------------------------------
__global__ __launch_bounds__(256) void attn_mfma(
    const __hip_bfloat16* __restrict__ qkvb,
    const __hip_bfloat16* __restrict__ vt,
    __hip_bfloat16* __restrict__ out)
{
    __shared__ __align__(16) __hip_bfloat16 Qs[2][128][32];
    __shared__ __align__(16) __hip_bfloat16 Ks[2][64][32];
    __shared__ __align__(16) __hip_bfloat16 Vs[2][64][32];
    __shared__ __align__(16) __hip_bfloat16 Ps[4][2][32][32];
    __shared__ float Lw[4][2][16];

    const int bh = blockIdx.x;
    const int b = bh >> 4, h = bh & 15;
    const int q0 = blockIdx.y * 128;
    const int tid = threadIdx.x;
    const int w = tid >> 6, lane = tid & 63;
    const int l15 = lane & 15, l4 = lane >> 4;
    const size_t ldq = 3 * D_;

    {
        #pragma unroll
        for (int c = 0; c < 2; ++c)
            #pragma unroll
            for (int it = 0; it < 2; ++it) {
                const int ch = it * 256 + tid;
                const int r = ch >> 2, cp = ch & 3;
                int qr = q0 + r; qr = (qr < T_) ? qr : (T_ - 1);
                const __hip_bfloat16* src = qkvb + (size_t)(b * T_ + qr) * ldq + h * 64 + c * 32 + cp * 8;
                __builtin_amdgcn_global_load_lds(
                    (const __attribute__((address_space(1))) unsigned*)src,
                    (__attribute__((address_space(3))) unsigned*)((__attribute__((address_space(3))) char*)&Qs[c][0][0] + ch * 16),
                    16, 0, 0);
            }
    }
    __syncthreads();
    bf16x8 qreg[2][2];
    #pragma unroll
    for (int qf = 0; qf < 2; ++qf)
        #pragma unroll
        for (int c = 0; c < 2; ++c)
            qreg[qf][c] = *(const bf16x8*)&Qs[c][w * 32 + qf * 16 + l15][l4 * 8];

    f32x4 of[2][4] = {};
    float lp[2] = {0.f, 0.f};
    const int qmaxw = q0 + w * 32 + 31;
    const int kend = (q0 + 128 < T_) ? (q0 + 128) : T_;

    for (int k0 = 0; k0 < kend; k0 += 64) {
        __syncthreads();
        {
            const int r = tid >> 2, cp = tid & 3;
            #pragma unroll
            for (int c = 0; c < 2; ++c) {
                int kr = k0 + r; kr = (kr < T_) ? kr : (T_ - 1);
                const __hip_bfloat16* srcK = qkvb + (size_t)(b * T_ + kr) * ldq + D_ + h * 64 + c * 32 + cp * 8;
                __builtin_amdgcn_global_load_lds(
                    (const __attribute__((address_space(1))) unsigned*)srcK,
                    (__attribute__((address_space(3))) unsigned*)((__attribute__((address_space(3))) char*)&Ks[c][0][0] + tid * 16),
                    16, 0, 0);
                const __hip_bfloat16* srcV = vt + ((size_t)(b * 1024 + h * 64 + r)) * 1024 + k0 + c * 32 + cp * 8;
                __builtin_amdgcn_global_load_lds(
                    (const __attribute__((address_space(1))) unsigned*)srcV,
                    (__attribute__((address_space(3))) unsigned*)((__attribute__((address_space(3))) char*)&Vs[c][0][0] + tid * 16),
                    16, 0, 0);
            }
        }
        __syncthreads();

        if (k0 <= qmaxw) {
            f32x4 sf[4][2] = {};
            #pragma unroll
            for (int c = 0; c < 2; ++c) {
                bf16x8 kf[4];
                #pragma unroll
                for (int kfr = 0; kfr < 4; ++kfr)
                    kf[kfr] = *(const bf16x8*)&Ks[c][kfr * 16 + l15][l4 * 8];
                #pragma unroll
                for (int kfr = 0; kfr < 4; ++kfr)
                    #pragma unroll
                    for (int qf = 0; qf < 2; ++qf)
                        sf[kfr][qf] = __builtin_amdgcn_mfma_f32_16x16x32_bf16(
                            kf[kfr], qreg[qf][c], sf[kfr][qf], 0, 0, 0);
            }
            const bool needmask = (k0 + 63) > (q0 + w * 32);
            #pragma unroll
            for (int kfr = 0; kfr < 4; ++kfr) {
                #pragma unroll
                for (int qf = 0; qf < 2; ++qf) {
                    const int qg = q0 + w * 32 + qf * 16 + l15;
                    float p[4];
                    #pragma unroll
                    for (int i = 0; i < 4; ++i) {
                        const int kg = k0 + kfr * 16 + l4 * 4 + i;
                        float pv = __expf(sf[kfr][qf][i] * 0.125f);
                        if (needmask && kg > qg) pv = 0.f;
                        p[i] = pv;
                        lp[qf] += pv;
                    }
                    unsigned* dst = (unsigned*)&Ps[w][kfr >> 1][qf * 16 + l15][(kfr & 1) * 16 + l4 * 4];
                    dst[0] = pack_bf2(p[0], p[1]);
                    dst[1] = pack_bf2(p[2], p[3]);
                }
            }
            #pragma unroll
            for (int kc = 0; kc < 2; ++kc) {
                bf16x8 pa[2], vb[4];
                #pragma unroll
                for (int qf = 0; qf < 2; ++qf)
                    pa[qf] = *(const bf16x8*)&Ps[w][kc][qf * 16 + l15][l4 * 8];
                #pragma unroll
                for (int df = 0; df < 4; ++df)
                    vb[df] = *(const bf16x8*)&Vs[kc][df * 16 + l15][l4 * 8];
                #pragma unroll
                for (int qf = 0; qf < 2; ++qf)
                    #pragma unroll
                    for (int df = 0; df < 4; ++df)
                        of[qf][df] = __builtin_amdgcn_mfma_f32_16x16x32_bf16(
                            pa[qf], vb[df], of[qf][df], 0, 0, 0);
            }
        }
    }

    #pragma unroll
    for (int qf = 0; qf < 2; ++qf) {
        float v = lp[qf];
        v += __shfl_xor(v, 16);
        v += __shfl_xor(v, 32);
        if (l4 == 0) Lw[w][qf][l15] = v;
    }
    __syncthreads();
    #pragma unroll
    for (int qf = 0; qf < 2; ++qf) {
        float inv[4];
        #pragma unroll
        for (int i = 0; i < 4; ++i) inv[i] = 1.f / Lw[w][qf][l4 * 4 + i];
        #pragma unroll
        for (int df = 0; df < 4; ++df) {
            #pragma unroll
            for (int i = 0; i < 4; ++i) {
                const int qg = q0 + w * 32 + qf * 16 + l4 * 4 + i;
                if (qg < T_)
                    out[(size_t)(b * T_ + qg) * D_ + h * 64 + df * 16 + l15] =
                        __float2bfloat16(of[qf][df][i] * inv[i]);
            }
        }
    }
}

// ---------------------------------------------------------------------------
// add + LN (single), optional bf16 mirror.
// ---------------------------------------------------------------------------
__device__ inline void block_ln_stats(float4 v, float& mu, float& inv,
                                      float* ws, float* ws2, float* mu_s, float* inv_s)
{
    const int tid = threadIdx.x;
    float s  = v.x + v.y + v.z + v.w;
    float s2 = v.x * v.x + v.y * v.y + v.z * v.z + v.w * v.w;
    #pragma unroll
    for (int off = 32; off; off >>= 1) {
        s  += __shfl_down(s, off);
        s2 += __shfl_down(s2, off);
    }
    const int wid = tid >> 6;
    if ((tid & 63) == 0) { ws[wid] = s; ws2[wid] = s2; }
    __syncthreads();
    if (tid == 0) {
        float S  = ws[0] + ws[1] + ws[2] + ws[3];
        float S2 = ws2[0] + ws2[1] + ws2[2] + ws2[3];
        float m = S * (1.f / (float)D_);
        float var = S2 * (1.f / (float)D_) - m * m;
        *mu_s = m;
        *inv_s = rsqrtf(var + 1e-5f);
    }
    __syncthreads();
    mu = *mu_s; inv = *inv_s;
}

__global__ __launch_bounds__(256) void add_ln_kernel(
    float* __restrict__ x, const float* __restrict__ y, int ybcast,
    const float* __restrict__ g, const float* __restrict__ beta,
    __hip_bfloat16* __restrict__ xb)
{
    const int row = blockIdx.x;
    const int tid = threadIdx.x;
    __shared__ float ws[4], ws2[4], mu_s, inv_s;
    float4* xr = reinterpret_cast<float4*>(x + (size_t)row * D_);
    float4 v = xr[tid];
    if (y) {
        const float4* yr = reinterpret_cast<const float4*>(
            ybcast ? y : y + (size_t)row * D_);
        float4 wv = yr[tid];
        v.x += wv.x; v.y += wv.y; v.z += wv.z; v.w += wv.w;
    }
    float mu, inv;
    block_ln_stats(v, mu, inv, ws, ws2, &mu_s, &inv_s);
    const float4 gg = reinterpret_cast<const float4*>(g)[tid];
    const float4 bb = reinterpret_cast<const float4*>(beta)[tid];
    float4 o;
    o.x = (v.x - mu) * inv * gg.x + bb.x;
    o.y = (v.y - mu) * inv * gg.y + bb.y;
    o.z = (v.z - mu) * inv * gg.z + bb.z;
    o.w = (v.w - mu) * inv * gg.w + bb.w;
    xr[tid] = o;
    if (xb) {
        __hip_bfloat16* xo = xb + (size_t)row * D_ + tid * 4;
        xo[0] = __float2bfloat16(o.x);
        xo[1] = __float2bfloat16(o.y);
        xo[2] = __float2bfloat16(o.z);
        xo[3] = __float2bfloat16(o.w);
    }
}

// ---------------------------------------------------------------------------
// Fused: x = LN2( LN1(x + y) + cav ), write fp32 x and bf16 xb.
// Saves one full x read+write pass per layer (SA-res LN + CA-const LN).
// ---------------------------------------------------------------------------
__global__ __launch_bounds__(256) void add_ln2_kernel(
    float* __restrict__ x, const float* __restrict__ y,
    const float* __restrict__ cav,
    const float* __restrict__ g1, const float* __restrict__ b1,
    const float* __restrict__ g2, const float* __restrict__ b2,
    __hip_bfloat16* __restrict__ xb)
{
    const int row = blockIdx.x;
    const int tid = threadIdx.x;
    __shared__ float ws[4], ws2[4], mu_s, inv_s;
    float4* xr = reinterpret_cast<float4*>(x + (size_t)row * D_);
    float4 v = xr[tid];
    {
        const float4 wv = reinterpret_cast<const float4*>(y + (size_t)row * D_)[tid];
        v.x += wv.x; v.y += wv.y; v.z += wv.z; v.w += wv.w;
    }
    float mu, inv;
    block_ln_stats(v, mu, inv, ws, ws2, &mu_s, &inv_s);
    const float4 g1v = reinterpret_cast<const float4*>(g1)[tid];
    const float4 b1v = reinterpret_cast<const float4*>(b1)[tid];
    const float4 cv  = reinterpret_cast<const float4*>(cav)[tid];
    float4 u;
    u.x = (v.x - mu) * inv * g1v.x + b1v.x + cv.x;
    u.y = (v.y - mu) * inv * g1v.y + b1v.y + cv.y;
    u.z = (v.z - mu) * inv * g1v.z + b1v.z + cv.z;
    u.w = (v.w - mu) * inv * g1v.w + b1v.w + cv.w;
    __syncthreads();   // reuse of ws/ws2 in second reduction
    float mu2, inv2;
    block_ln_stats(u, mu2, inv2, ws, ws2, &mu_s, &inv_s);
    const float4 g2v = reinterpret_cast<const float4*>(g2)[tid];
    const float4 b2v = reinterpret_cast<const float4*>(b2)[tid];
    float4 o;
    o.x = (u.x - mu2) * inv2 * g2v.x + b2v.x;
    o.y = (u.y - mu2) * inv2 * g2v.y + b2v.y;
    o.z = (u.z - mu2) * inv2 * g2v.z + b2v.z;
    o.w = (u.w - mu2) * inv2 * g2v.w + b2v.w;
    xr[tid] = o;
    __hip_bfloat16* xo = xb + (size_t)row * D_ + tid * 4;
    xo[0] = __float2bfloat16(o.x);
    xo[1] = __float2bfloat16(o.y);
    xo[2] = __float2bfloat16(o.z);
    xo[3] = __float2bfloat16(o.w);
}

__global__ __launch_bounds__(256) void interleave_pe_kernel(
    const float* __restrict__ obs_tok, const float* __restrict__ act_tok,
    float* __restrict__ x, __hip_bfloat16* __restrict__ xb)
{
    const int row = blockIdx.x;
    const int b = row / T_;
    const int t = row - b * T_;
    const float* src = (t & 1)
        ? (act_tok + (size_t)(b * (S_ - 1) + (t >> 1)) * D_)
        : (obs_tok + (size_t)(b * S_ + (t >> 1)) * D_);
    float* xr = x + (size_t)row * D_;
    __hip_bfloat16* xo = xb + (size_t)row * D_;
    #pragma unroll
    for (int k = 0; k < 4; ++k) {
        int d = threadIdx.x + k * 256;
        float ang = (float)b * expf(-(float)(d & ~1) * (9.210340371976184f / 1024.0f));
        float pe = (d & 1) ? cosf(ang) : sinf(ang);
        float v = src[d] + pe;
        xr[d] = v;
        xo[d] = __float2bfloat16(v);
    }
}

// ---------------------------------------------------------------------------
// CA constant, split-K (deterministic, no atomics):
// part[ks][l*D+d] = sum_{k in ks*64..+64} bv[l][k] * w[l][k][d]
// then reduce: ca[l*D+d] = ca_b_out[l*D+d] + sum_ks part.
// ---------------------------------------------------------------------------
__global__ __launch_bounds__(256) void ca_part_kernel(
    const float* __restrict__ ca_b_in, const float* __restrict__ ca_w_out,
    float* __restrict__ part)
{
    const int idx = blockIdx.x * 256 + threadIdx.x;   // l*1024 + d
    const int ks = blockIdx.y;                         // 0..15
    const int l = idx >> 10, d = idx & 1023;
    const float* bv = ca_b_in + (size_t)l * 3 * D_ + 2 * D_ + ks * 64;
    const float* wp = ca_w_out + (size_t)l * D_ * D_ + (size_t)(ks * 64) * D_ + d;
    float s = 0.f;
    #pragma unroll 8
    for (int k = 0; k < 64; ++k) s = fmaf(bv[k], wp[(size_t)k * D_], s);
    part[(size_t)ks * (L_ * D_) + idx] = s;
}

__global__ __launch_bounds__(256) void ca_reduce_kernel(
    const float* __restrict__ part, const float* __restrict__ ca_b_out,
    float* __restrict__ out)
{
    const int idx = blockIdx.x * 256 + threadIdx.x;
    float s = ca_b_out[idx];
    #pragma unroll
    for (int ks = 0; ks < 16; ++ks) s += part[(size_t)ks * (L_ * D_) + idx];
    out[idx] = s;
}

// ---------------------------------------------------------------------------
extern "C" void kernel_launch(void* const* d_in, const int* in_sizes, int n_in,
                              void* d_out, int out_size, void* d_ws, size_t ws_size,
                              hipStream_t stream)
{
    const float* obs     = (const float*)d_in[0];
    const float* act     = (const float*)d_in[1];
    const float* in_w1   = (const float*)d_in[2];
    const float* in_b1   = (const float*)d_in[3];
    const float* in_w2   = (const float*)d_in[4];
    const float* in_b2   = (const float*)d_in[5];
    const float* in_w3   = (const float*)d_in[6];
    const float* in_b3   = (const float*)d_in[7];
    const float* act_w1  = (const float*)d_in[8];
    const float* act_b1  = (const float*)d_in[9];
    const float* act_w2  = (const float*)d_in[10];
    const float* act_b2  = (const float*)d_in[11];
    const float* act_w3  = (const float*)d_in[12];
    const float* act_b3  = (const float*)d_in[13];
    const float* out_w1  = (const float*)d_in[14];
    const float* out_b1  = (const float*)d_in[15];
    const float* out_w2  = (const float*)d_in[16];
    const float* out_b2  = (const float*)d_in[17];
    const float* out_w3  = (const float*)d_in[18];
    const float* out_b3  = (const float*)d_in[19];
    const float* sa_w_in = (const float*)d_in[20];
    const float* sa_b_in = (const float*)d_in[21];
    const float* sa_w_out= (const float*)d_in[22];
    const float* sa_b_out= (const float*)d_in[23];
    const float* ca_b_in = (const float*)d_in[25];
    const float* ca_w_out= (const float*)d_in[26];
    const float* ca_b_out= (const float*)d_in[27];
    const float* ff_w1   = (const float*)d_in[28];
    const float* ff_b1   = (const float*)d_in[29];
    const float* ff_w2   = (const float*)d_in[30];
    const float* ff_b2   = (const float*)d_in[31];
    const float* ln1_g   = (const float*)d_in[32];
    const float* ln1_b   = (const float*)d_in[33];
    const float* ln2_g   = (const float*)d_in[34];
    const float* ln2_b   = (const float*)d_in[35];
    const float* ln3_g   = (const float*)d_in[36];
    const float* ln3_b   = (const float*)d_in[37];
    const float* lnf_g   = (const float*)d_in[38];
    const float* lnf_b   = (const float*)d_in[39];

    const int MT = B_ * T_;          // 4092
    const int Mo = B_ * S_;          // 2048
    const int Ma = B_ * (S_ - 1);    // 2044

    char* base = (char*)d_ws;
    size_t used = 0;
    auto alloc = [&](size_t bytes) -> char* {
        char* r = base + used;
        used += (bytes + 255) & ~(size_t)255;
        return r;
    };
    typedef __hip_bfloat16 bf;
    bf* wi1  = (bf*)alloc((size_t)1024 * 64 * 2);
    bf* wi2  = (bf*)alloc((size_t)1024 * 1024 * 2);
    bf* wi3  = (bf*)alloc((size_t)1024 * 1024 * 2);
    bf* wa1  = (bf*)alloc((size_t)1024 * 32 * 2);
    bf* wa2  = (bf*)alloc((size_t)1024 * 1024 * 2);
    bf* wa3  = (bf*)alloc((size_t)1024 * 1024 * 2);
    bf* wo1  = (bf*)alloc((size_t)1024 * 1024 * 2);
    bf* wo2  = (bf*)alloc((size_t)1024 * 1024 * 2);
    bf* wo3  = (bf*)alloc((size_t)16 * 1024 * 2);
    bf* wsin = (bf*)alloc((size_t)L_ * 3072 * 1024 * 2);
    bf* wsout= (bf*)alloc((size_t)L_ * 1024 * 1024 * 2);
    bf* wf1  = (bf*)alloc((size_t)L_ * 4096 * 1024 * 2);
    bf* wf2  = (bf*)alloc((size_t)L_ * 1024 * 4096 * 2);
    bf* obs_bf = (bf*)alloc((size_t)Mo * 64 * 2);
    bf* act_bf = (bf*)alloc((size_t)Ma * 32 * 2);
    bf* x_bf   = (bf*)alloc((size_t)MT * D_ * 2);
    bf* attnb  = (bf*)alloc((size_t)MT * D_ * 2);
    bf* h1b    = (bf*)alloc((size_t)MT * D_ * 2);
    bf* h2b    = (bf*)alloc((size_t)MT * D_ * 2);
    char* shared_rg = alloc((size_t)MT * F_ * 2);   // qkvb (25.1MB) | ffh (33.5MB)
    bf* qkvb = (bf*)shared_rg;
    bf* ffh  = (bf*)shared_rg;
    bf* vt   = (bf*)alloc((size_t)B_ * 1024 * 1024 * 2);
    float* x       = (float*)alloc((size_t)MT * D_ * 4);
    float* y       = (float*)alloc((size_t)MT * D_ * 4);
    float* obs_tok = (float*)alloc((size_t)Mo * D_ * 4);
    float* act_tok = (float*)alloc((size_t)Ma * D_ * 4);
    float* ca      = (float*)alloc((size_t)L_ * D_ * 4);
    float* ca_part = (float*)alloc((size_t)16 * L_ * D_ * 4);
    if (used > ws_size) return;

    auto tw = [&](const float* W, bf* Wt, int K, int N, int Kpad, int batch) {
        dim3 g((N + 31) / 32, (Kpad + 31) / 32, batch);
        transpose_w<<<g, 256, 0, stream>>>(W, Wt, K, N, Kpad);
    };
    auto gemm = [&](const bf* A, const bf* Wt, const float* bias,
                    float* Cf, bf* Cb, int M, int K, int N, int relu) {
        dim3 g((N + 127) / 128, (M + 127) / 128);
        gemm_bf16<<<g, 256, 0, stream>>>(A, Wt, bias, Cf, Cb, M, K, N, relu);
    };

    tw(in_w1,  wi1, 64,   1024, 64,   1);
    tw(in_w2,  wi2, 1024, 1024, 1024, 1);
    tw(in_w3,  wi3, 1024, 1024, 1024, 1);
    tw(act_w1, wa1, 16,   1024, 32,   1);
    tw(act_w2, wa2, 1024, 1024, 1024, 1);
    tw(act_w3, wa3, 1024, 1024, 1024, 1);
    tw(out_w1, wo1, 1024, 1024, 1024, 1);
    tw(out_w2, wo2, 1024, 1024, 1024, 1);
    tw(out_w3, wo3, 1024, 16,   1024, 1);
    tw(sa_w_in,  wsin,  1024, 3072, 1024, L_);
    tw(sa_w_out, wsout, 1024, 1024, 1024, L_);
    tw(ff_w1,    wf1,   1024, 4096, 1024, L_);
    tw(ff_w2,    wf2,   4096, 1024, 4096, L_);

    convert_pad<<<(Mo * 64 + 255) / 256, 256, 0, stream>>>(obs, obs_bf, Mo, 64, 64);
    convert_pad<<<(Ma * 32 + 255) / 256, 256, 0, stream>>>(act, act_bf, Ma, 16, 32);
    ca_part_kernel<<<dim3((L_ * D_) / 256, 16), 256, 0, stream>>>(ca_b_in, ca_w_out, ca_part);
    ca_reduce_kernel<<<(L_ * D_) / 256, 256, 0, stream>>>(ca_part, ca_b_out, ca);

    // ---- input MLPs ----
    gemm(obs_bf, wi1, in_b1, nullptr, h1b, Mo, 64,   D_, 1);
    gemm(h1b,    wi2, in_b2, nullptr, h2b, Mo, D_,   D_, 1);
    gemm(h2b,    wi3, in_b3, obs_tok, nullptr, Mo, D_, D_, 0);
    gemm(act_bf, wa1, act_b1, nullptr, h1b, Ma, 32,  D_, 1);
    gemm(h1b,    wa2, act_b2, nullptr, h2b, Ma, D_,  D_, 1);
    gemm(h2b,    wa3, act_b3, act_tok, nullptr, Ma, D_, D_, 0);

    interleave_pe_kernel<<<MT, 256, 0, stream>>>(obs_tok, act_tok, x, x_bf);

    // ---- decoder layers ----
    for (int l = 0; l < L_; ++l) {
        gemm(x_bf, wsin + (size_t)l * 3072 * 1024, sa_b_in + (size_t)l * 3 * D_,
             nullptr, qkvb, MT, D_, 3 * D_, 0);
        v_transpose<<<dim3(32, 32, B_), 256, 0, stream>>>(qkvb, vt);
        attn_mfma<<<dim3(B_ * H_, 8), 256, 0, stream>>>(qkvb, vt, attnb);
        gemm(attnb, wsout + (size_t)l * 1024 * 1024, sa_b_out + (size_t)l * D_,
             y, nullptr, MT, D_, D_, 0);
        add_ln2_kernel<<<MT, 256, 0, stream>>>(x, y, ca + (size_t)l * D_,
             ln1_g + (size_t)l * D_, ln1_b + (size_t)l * D_,
             ln2_g + (size_t)l * D_, ln2_b + (size_t)l * D_, x_bf);
        gemm(x_bf, wf1 + (size_t)l * 4096 * 1024, ff_b1 + (size_t)l * F_,
             nullptr, ffh, MT, D_, F_, 1);
        gemm(ffh, wf2 + (size_t)l * 1024 * 4096, ff_b2 + (size_t)l * D_,
             y, nullptr, MT, F_, D_, 0);
        add_ln_kernel<<<MT, 256, 0, stream>>>(x, y, 0,
             ln3_g + (size_t)l * D_, ln3_b + (size_t)l * D_, x_bf);
    }

    // ---- final norm + output MLP ----
    add_ln_kernel<<<MT, 256, 0, stream>>>(x, nullptr, 0, lnf_g, lnf_b, x_bf);
    gemm(x_bf, wo1, out_b1, nullptr, h1b, MT, D_, D_, 1);
    gemm(h1b,  wo2, out_b2, nullptr, h2b, MT, D_, D_, 1);
    gemm(h2b,  wo3, out_b3, (float*)d_out, nullptr, MT, D_, 16, 0);
}

// Round 5
// 1652.274 us; speedup vs baseline: 8.9028x; 1.0222x over previous
//
#include <hip/hip_runtime.h>
#include <hip/hip_bf16.h>
#include <cstdint>
#include <cstddef>

#define B_  4
#define S_  512
#define T_  1023
#define D_  1024
#define H_  16
#define DH_ 64
#define F_  4096
#define L_  4

typedef float f32x4 __attribute__((ext_vector_type(4)));
typedef __bf16 bf16x8 __attribute__((ext_vector_type(8)));

__device__ inline unsigned pack_bf2(float a, float b) {
    union { __hip_bfloat16 h; unsigned short u; } ua, ub;
    ua.h = __float2bfloat16(a); ub.h = __float2bfloat16(b);
    return (unsigned)ua.u | ((unsigned)ub.u << 16);
}

// ---------------------------------------------------------------------------
// bf16 MFMA GEMM: depth-2 counted-vmcnt pipeline (3 LDS buffers, 48 KB) +
// XOR bank-swizzle (pre-swizzled global source, swizzled ds_read — rule #21).
// C[M,N] = op(A[M,K] @ Wt[N,K]^T + bias). 128x128 tile, BK=32, 4 waves (2x2).
// Main loop never drains vmcnt to 0; raw s_barrier (no implicit drain).
// ---------------------------------------------------------------------------
__global__ __launch_bounds__(256) void gemm_bf16(
    const __hip_bfloat16* __restrict__ A, const __hip_bfloat16* __restrict__ Wt,
    const float* __restrict__ bias,
    float* __restrict__ Cf, __hip_bfloat16* __restrict__ Cb,
    int M, int K, int N, int relu)
{
    __shared__ __align__(16) __hip_bfloat16 Asm[3][128 * 32];
    __shared__ __align__(16) __hip_bfloat16 Bsm[3][128 * 32];
    const int tid  = threadIdx.x;
    const int lane = tid & 63;
    const int w    = tid >> 6;
    const int wr   = w >> 1, wc = w & 1;
    const int l15  = lane & 15, l4 = lane >> 4;

    // bijective XCD-aware swizzle (m204)
    const int gx = gridDim.x;
    int bid = blockIdx.y * gx + blockIdx.x;
    {
        const int nwg = gx * gridDim.y;
        const int q = nwg >> 3, r = nwg & 7;
        const int xcd = bid & 7, idx = bid >> 3;
        bid = (xcd < r ? xcd * (q + 1) : r * (q + 1) + (xcd - r) * q) + idx;
    }
    const int row0 = (bid / gx) * 128;
    const int col0 = (bid % gx) * 128;

    f32x4 acc[4][4] = {};

    // stage: LDS dest linear (global_load_lds constraint); SOURCE column
    // pre-swizzled by the involution slot^=(row&3) so swizzled reads see
    // the right data (m173 / rule #21).
    auto stage = [&](int buf, int kt) {
        auto* ldsA = (__attribute__((address_space(3))) char*)&Asm[buf][0];
        auto* ldsB = (__attribute__((address_space(3))) char*)&Bsm[buf][0];
        #pragma unroll
        for (int half = 0; half < 2; ++half) {
            const int ch = half * 256 + tid;            // 16B chunk id
            const int r  = ch >> 2;
            const int c  = ((ch & 3) ^ (r & 3)) * 8;    // inverse-swizzled col
            int gr = row0 + r; gr = (gr < M) ? gr : (M - 1);
            const __hip_bfloat16* srcA = A + (size_t)gr * K + kt + c;
            __builtin_amdgcn_global_load_lds(
                (const __attribute__((address_space(1))) unsigned*)srcA,
                (__attribute__((address_space(3))) unsigned*)(ldsA + (size_t)ch * 16),
                16, 0, 0);
            int gc = col0 + r; gc = (gc < N) ? gc : (N - 1);
            const __hip_bfloat16* srcB = Wt + (size_t)gc * K + kt + c;
            __builtin_amdgcn_global_load_lds(
                (const __attribute__((address_space(1))) unsigned*)srcB,
                (__attribute__((address_space(3))) unsigned*)(ldsB + (size_t)ch * 16),
                16, 0, 0);
        }
    };
    // compute: swizzled ds_read — slot = l4 ^ (row&3), row&3 == l15&3 here,
    // so the swizzle is a per-lane constant. 16 lanes cover all 32 banks
    // at 2-way aliasing (free per m136).
    auto compute = [&](int buf) {
        const int swz = (l4 ^ (l15 & 3)) * 8;
        const __hip_bfloat16* ab = &Asm[buf][(size_t)(wr * 64 + l15) * 32] + swz;
        const __hip_bfloat16* bb = &Bsm[buf][(size_t)(wc * 64 + l15) * 32] + swz;
        bf16x8 af[4], bf[4];
        #pragma unroll
        for (int mi = 0; mi < 4; ++mi) af[mi] = *(const bf16x8*)(ab + mi * 16 * 32);
        #pragma unroll
        for (int nj = 0; nj < 4; ++nj) bf[nj] = *(const bf16x8*)(bb + nj * 16 * 32);
        #pragma unroll
        for (int mi = 0; mi < 4; ++mi)
            #pragma unroll
            for (int nj = 0; nj < 4; ++nj)
                acc[mi][nj] = __builtin_amdgcn_mfma_f32_16x16x32_bf16(
                    af[mi], bf[nj], acc[mi][nj], 0, 0, 0);
    };

    const int nk = K >> 5;
    stage(0, 0);
    if (nk > 1) stage(1, 32);
    int cur = 0;
    for (int t = 0; t < nk; ++t) {
        // counted wait: tile t's 4 loads done; tile t+1 stays in flight
        if (t + 1 < nk) asm volatile("s_waitcnt vmcnt(4)" ::: "memory");
        else            asm volatile("s_waitcnt vmcnt(0)" ::: "memory");
        __builtin_amdgcn_sched_barrier(0);
        __builtin_amdgcn_s_barrier();          // raw: no vmcnt drain
        __builtin_amdgcn_sched_barrier(0);
        if (t + 2 < nk) {                      // issue next-next tile BEFORE compute
            const int nb = (cur >= 1) ? cur - 1 : cur + 2;   // (cur+2)%3
            stage(nb, (t + 2) * 32);
        }
        compute(cur);
        cur = (cur == 2) ? 0 : cur + 1;
    }

    // epilogue: C/D layout col = lane&15, row = (lane>>4)*4 + i  [m89-verified]
    #pragma unroll
    for (int nj = 0; nj < 4; ++nj) {
        const int c = col0 + wc * 64 + nj * 16 + l15;
        if (c >= N) continue;
        const float bv = bias[c];
        #pragma unroll
        for (int mi = 0; mi < 4; ++mi) {
            #pragma unroll
            for (int i = 0; i < 4; ++i) {
                const int r = row0 + wr * 64 + mi * 16 + l4 * 4 + i;
                if (r >= M) continue;
                float v = acc[mi][nj][i] + bv;
                if (relu) v = fmaxf(v, 0.f);
                if (Cf) Cf[(size_t)r * N + c] = v;
                if (Cb) Cb[(size_t)r * N + c] = __float2bfloat16(v);
            }
        }
    }
}

// ---------------------------------------------------------------------------
// Weight transpose+convert (unchanged).
// ---------------------------------------------------------------------------
__global__ __launch_bounds__(256) void transpose_w(
    const float* __restrict__ W, __hip_bfloat16* __restrict__ Wt,
    int K, int N, int Kpad)
{
    __shared__ float t[32][33];
    W  += (size_t)blockIdx.z * K * N;
    Wt += (size_t)blockIdx.z * N * Kpad;
    const int n0 = blockIdx.x * 32, k0 = blockIdx.y * 32;
    const int tx = threadIdx.x & 31, ty = threadIdx.x >> 5;
    #pragma unroll
    for (int i = 0; i < 4; ++i) {
        int r = ty + i * 8;
        int k = k0 + r, n = n0 + tx;
        t[r][tx] = (k < K && n < N) ? W[(size_t)k * N + n] : 0.f;
    }
    __syncthreads();
    #pragma unroll
    for (int i = 0; i < 4; ++i) {
        int r = ty + i * 8;
        int n = n0 + r, k = k0 + tx;
        if (n < N && k < Kpad) Wt[(size_t)n * Kpad + k] = __float2bfloat16(t[tx][r]);
    }
}

__global__ __launch_bounds__(256) void convert_pad(
    const float* __restrict__ in, __hip_bfloat16* __restrict__ out,
    int M, int Kin, int Kout)
{
    int idx = blockIdx.x * 256 + threadIdx.x;
    if (idx >= M * Kout) return;
    int r = idx / Kout, c = idx - r * Kout;
    out[idx] = __float2bfloat16(c < Kin ? in[(size_t)r * Kin + c] : 0.f);
}

// ---------------------------------------------------------------------------
// V transpose (unchanged): vt[b][c][t] = qkvb[b*T+t][2048+c], pad t>=T -> 0.
// ---------------------------------------------------------------------------
__global__ __launch_bounds__(256) void v_transpose(
    const __hip_bfloat16* __restrict__ qkvb, __hip_bfloat16* __restrict__ vt)
{
    __shared__ __hip_bfloat16 tile[32][33];
    const int b  = blockIdx.z;
    const int c0 = blockIdx.x * 32;
    const int t0 = blockIdx.y * 32;
    const int tx = threadIdx.x & 31, ty = threadIdx.x >> 5;
    const __hip_bfloat16 z = __float2bfloat16(0.f);
    #pragma unroll
    for (int i = 0; i < 4; ++i) {
        const int tl = ty + i * 8;
        const int t = t0 + tl;
        tile[tl][tx] = (t < T_) ? qkvb[(size_t)(b * T_ + t) * 3072 + 2048 + c0 + tx] : z;
    }
    __syncthreads();
    #pragma unroll
    for (int i = 0; i < 4; ++i) {
        const int cl = ty + i * 8;
        const int t = t0 + tx;
        vt[((size_t)(b * 1024 + c0 + cl)) * 1024 + t] = (t < T_) ? tile[tx][cl] : z;
    }
}

// ---------------------------------------------------------------------------
// MFMA flash attention (unchanged from round 3 — proven).
// ---------------------------------------------------------------------------
__global__ __launch_bounds__(256) void attn_mfma(
    const __hip_bfloat16* __restrict__ qkvb,
    const __hip_bfloat16* __restrict__ vt,
    __hip_bfloat16* __restrict__ out)
{
    __shared__ __align__(16) __hip_bfloat16 Qs[2][128][32];
    __shared__ __align__(16) __hip_bfloat16 Ks[2][64][32];
    __shared__ __align__(16) __hip_bfloat16 Vs[2][64][32];
    __shared__ __align__(16) __hip_bfloat16 Ps[4][2][32][32];
    __shared__ float Lw[4][2][16];

    const int bh = blockIdx.x;
    const int b = bh >> 4, h = bh & 15;
    const int q0 = blockIdx.y * 128;
    const int tid = threadIdx.x;
    const int w = tid >> 6, lane = tid & 63;
    const int l15 = lane & 15, l4 = lane >> 4;
    const size_t ldq = 3 * D_;

    {
        #pragma unroll
        for (int c = 0; c < 2; ++c)
            #pragma unroll
            for (int it = 0; it < 2; ++it) {
                const int ch = it * 256 + tid;
                const int r = ch >> 2, cp = ch & 3;
                int qr = q0 + r; qr = (qr < T_) ? qr : (T_ - 1);
                const __hip_bfloat16* src = qkvb + (size_t)(b * T_ + qr) * ldq + h * 64 + c * 32 + cp * 8;
                __builtin_amdgcn_global_load_lds(
                    (const __attribute__((address_space(1))) unsigned*)src,
                    (__attribute__((address_space(3))) unsigned*)((__attribute__((address_space(3))) char*)&Qs[c][0][0] + ch * 16),
                    16, 0, 0);
            }
    }
    __syncthreads();
    bf16x8 qreg[2][2];
    #pragma unroll
    for (int qf = 0; qf < 2; ++qf)
        #pragma unroll
        for (int c = 0; c < 2; ++c)
            qreg[qf][c] = *(const bf16x8*)&Qs[c][w * 32 + qf * 16 + l15][l4 * 8];

    f32x4 of[2][4] = {};
    float lp[2] = {0.f, 0.f};
    const int qmaxw = q0 + w * 32 + 31;
    const int kend = (q0 + 128 < T_) ? (q0 + 128) : T_;

    for (int k0 = 0; k0 < kend; k0 += 64) {
        __syncthreads();
        {
            const int r = tid >> 2, cp = tid & 3;
            #pragma unroll
            for (int c = 0; c < 2; ++c) {
                int kr = k0 + r; kr = (kr < T_) ? kr : (T_ - 1);
                const __hip_bfloat16* srcK = qkvb + (size_t)(b * T_ + kr) * ldq + D_ + h * 64 + c * 32 + cp * 8;
                __builtin_amdgcn_global_load_lds(
                    (const __attribute__((address_space(1))) unsigned*)srcK,
                    (__attribute__((address_space(3))) unsigned*)((__attribute__((address_space(3))) char*)&Ks[c][0][0] + tid * 16),
                    16, 0, 0);
                const __hip_bfloat16* srcV = vt + ((size_t)(b * 1024 + h * 64 + r)) * 1024 + k0 + c * 32 + cp * 8;
                __builtin_amdgcn_global_load_lds(
                    (const __attribute__((address_space(1))) unsigned*)srcV,
                    (__attribute__((address_space(3))) unsigned*)((__attribute__((address_space(3))) char*)&Vs[c][0][0] + tid * 16),
                    16, 0, 0);
            }
        }
        __syncthreads();

        if (k0 <= qmaxw) {
            f32x4 sf[4][2] = {};
            #pragma unroll
            for (int c = 0; c < 2; ++c) {
                bf16x8 kf[4];
                #pragma unroll
                for (int kfr = 0; kfr < 4; ++kfr)
                    kf[kfr] = *(const bf16x8*)&Ks[c][kfr * 16 + l15][l4 * 8];
                #pragma unroll
                for (int kfr = 0; kfr < 4; ++kfr)
                    #pragma unroll
                    for (int qf = 0; qf < 2; ++qf)
                        sf[kfr][qf] = __builtin_amdgcn_mfma_f32_16x16x32_bf16(
                            kf[kfr], qreg[qf][c], sf[kfr][qf], 0, 0, 0);
            }
            const bool needmask = (k0 + 63) > (q0 + w * 32);
            #pragma unroll
            for (int kfr = 0; kfr < 4; ++kfr) {
                #pragma unroll
                for (int qf = 0; qf < 2; ++qf) {
                    const int qg = q0 + w * 32 + qf * 16 + l15;
                    float p[4];
                    #pragma unroll
                    for (int i = 0; i < 4; ++i) {
                        const int kg = k0 + kfr * 16 + l4 * 4 + i;
                        float pv = __expf(sf[kfr][qf][i] * 0.125f);
                        if (needmask && kg > qg) pv = 0.f;
                        p[i] = pv;
                        lp[qf] += pv;
                    }
                    unsigned* dst = (unsigned*)&Ps[w][kfr >> 1][qf * 16 + l15][(kfr & 1) * 16 + l4 * 4];
                    dst[0] = pack_bf2(p[0], p[1]);
                    dst[1] = pack_bf2(p[2], p[3]);
                }
            }
            #pragma unroll
            for (int kc = 0; kc < 2; ++kc) {
                bf16x8 pa[2], vb[4];
                #pragma unroll
                for (int qf = 0; qf < 2; ++qf)
                    pa[qf] = *(const bf16x8*)&Ps[w][kc][qf * 16 + l15][l4 * 8];
                #pragma unroll
                for (int df = 0; df < 4; ++df)
                    vb[df] = *(const bf16x8*)&Vs[kc][df * 16 + l15][l4 * 8];
                #pragma unroll
                for (int qf = 0; qf < 2; ++qf)
                    #pragma unroll
                    for (int df = 0; df < 4; ++df)
                        of[qf][df] = __builtin_amdgcn_mfma_f32_16x16x32_bf16(
                            pa[qf], vb[df], of[qf][df], 0, 0, 0);
            }
        }
    }

    #pragma unroll
    for (int qf = 0; qf < 2; ++qf) {
        float v = lp[qf];
        v += __shfl_xor(v, 16);
        v += __shfl_xor(v, 32);
        if (l4 == 0) Lw[w][qf][l15] = v;
    }
    __syncthreads();
    #pragma unroll
    for (int qf = 0; qf < 2; ++qf) {
        float inv[4];
        #pragma unroll
        for (int i = 0; i < 4; ++i) inv[i] = 1.f / Lw[w][qf][l4 * 4 + i];
        #pragma unroll
        for (int df = 0; df < 4; ++df) {
            #pragma unroll
            for (int i = 0; i < 4; ++i) {
                const int qg = q0 + w * 32 + qf * 16 + l4 * 4 + i;
                if (qg < T_)
                    out[(size_t)(b * T_ + qg) * D_ + h * 64 + df * 16 + l15] =
                        __float2bfloat16(of[qf][df][i] * inv[i]);
            }
        }
    }
}

// ---------------------------------------------------------------------------
// LN helpers + fused kernels (unchanged).
// ---------------------------------------------------------------------------
__device__ inline void block_ln_stats(float4 v, float& mu, float& inv,
                                      float* ws, float* ws2, float* mu_s, float* inv_s)
{
    const int tid = threadIdx.x;
    float s  = v.x + v.y + v.z + v.w;
    float s2 = v.x * v.x + v.y * v.y + v.z * v.z + v.w * v.w;
    #pragma unroll
    for (int off = 32; off; off >>= 1) {
        s  += __shfl_down(s, off);
        s2 += __shfl_down(s2, off);
    }
    const int wid = tid >> 6;
    if ((tid & 63) == 0) { ws[wid] = s; ws2[wid] = s2; }
    __syncthreads();
    if (tid == 0) {
        float S  = ws[0] + ws[1] + ws[2] + ws[3];
        float S2 = ws2[0] + ws2[1] + ws2[2] + ws2[3];
        float m = S * (1.f / (float)D_);
        float var = S2 * (1.f / (float)D_) - m * m;
        *mu_s = m;
        *inv_s = rsqrtf(var + 1e-5f);
    }
    __syncthreads();
    mu = *mu_s; inv = *inv_s;
}

__global__ __launch_bounds__(256) void add_ln_kernel(
    float* __restrict__ x, const float* __restrict__ y, int ybcast,
    const float* __restrict__ g, const float* __restrict__ beta,
    __hip_bfloat16* __restrict__ xb)
{
    const int row = blockIdx.x;
    const int tid = threadIdx.x;
    __shared__ float ws[4], ws2[4], mu_s, inv_s;
    float4* xr = reinterpret_cast<float4*>(x + (size_t)row * D_);
    float4 v = xr[tid];
    if (y) {
        const float4* yr = reinterpret_cast<const float4*>(
            ybcast ? y : y + (size_t)row * D_);
        float4 wv = yr[tid];
        v.x += wv.x; v.y += wv.y; v.z += wv.z; v.w += wv.w;
    }
    float mu, inv;
    block_ln_stats(v, mu, inv, ws, ws2, &mu_s, &inv_s);
    const float4 gg = reinterpret_cast<const float4*>(g)[tid];
    const float4 bb = reinterpret_cast<const float4*>(beta)[tid];
    float4 o;
    o.x = (v.x - mu) * inv * gg.x + bb.x;
    o.y = (v.y - mu) * inv * gg.y + bb.y;
    o.z = (v.z - mu) * inv * gg.z + bb.z;
    o.w = (v.w - mu) * inv * gg.w + bb.w;
    xr[tid] = o;
    if (xb) {
        __hip_bfloat16* xo = xb + (size_t)row * D_ + tid * 4;
        xo[0] = __float2bfloat16(o.x);
        xo[1] = __float2bfloat16(o.y);
        xo[2] = __float2bfloat16(o.z);
        xo[3] = __float2bfloat16(o.w);
    }
}

__global__ __launch_bounds__(256) void add_ln2_kernel(
    float* __restrict__ x, const float* __restrict__ y,
    const float* __restrict__ cav,
    const float* __restrict__ g1, const float* __restrict__ b1,
    const float* __restrict__ g2, const float* __restrict__ b2,
    __hip_bfloat16* __restrict__ xb)
{
    const int row = blockIdx.x;
    const int tid = threadIdx.x;
    __shared__ float ws[4], ws2[4], mu_s, inv_s;
    float4* xr = reinterpret_cast<float4*>(x + (size_t)row * D_);
    float4 v = xr[tid];
    {
        const float4 wv = reinterpret_cast<const float4*>(y + (size_t)row * D_)[tid];
        v.x += wv.x; v.y += wv.y; v.z += wv.z; v.w += wv.w;
    }
    float mu, inv;
    block_ln_stats(v, mu, inv, ws, ws2, &mu_s, &inv_s);
    const float4 g1v = reinterpret_cast<const float4*>(g1)[tid];
    const float4 b1v = reinterpret_cast<const float4*>(b1)[tid];
    const float4 cv  = reinterpret_cast<const float4*>(cav)[tid];
    float4 u;
    u.x = (v.x - mu) * inv * g1v.x + b1v.x + cv.x;
    u.y = (v.y - mu) * inv * g1v.y + b1v.y + cv.y;
    u.z = (v.z - mu) * inv * g1v.z + b1v.z + cv.z;
    u.w = (v.w - mu) * inv * g1v.w + b1v.w + cv.w;
    __syncthreads();
    float mu2, inv2;
    block_ln_stats(u, mu2, inv2, ws, ws2, &mu_s, &inv_s);
    const float4 g2v = reinterpret_cast<const float4*>(g2)[tid];
    const float4 b2v = reinterpret_cast<const float4*>(b2)[tid];
    float4 o;
    o.x = (u.x - mu2) * inv2 * g2v.x + b2v.x;
    o.y = (u.y - mu2) * inv2 * g2v.y + b2v.y;
    o.z = (u.z - mu2) * inv2 * g2v.z + b2v.z;
    o.w = (u.w - mu2) * inv2 * g2v.w + b2v.w;
    xr[tid] = o;
    __hip_bfloat16* xo = xb + (size_t)row * D_ + tid * 4;
    xo[0] = __float2bfloat16(o.x);
    xo[1] = __float2bfloat16(o.y);
    xo[2] = __float2bfloat16(o.z);
    xo[3] = __float2bfloat16(o.w);
}

__global__ __launch_bounds__(256) void interleave_pe_kernel(
    const float* __restrict__ obs_tok, const float* __restrict__ act_tok,
    float* __restrict__ x, __hip_bfloat16* __restrict__ xb)
{
    const int row = blockIdx.x;
    const int b = row / T_;
    const int t = row - b * T_;
    const float* src = (t & 1)
        ? (act_tok + (size_t)(b * (S_ - 1) + (t >> 1)) * D_)
        : (obs_tok + (size_t)(b * S_ + (t >> 1)) * D_);
    float* xr = x + (size_t)row * D_;
    __hip_bfloat16* xo = xb + (size_t)row * D_;
    #pragma unroll
    for (int k = 0; k < 4; ++k) {
        int d = threadIdx.x + k * 256;
        float ang = (float)b * expf(-(float)(d & ~1) * (9.210340371976184f / 1024.0f));
        float pe = (d & 1) ? cosf(ang) : sinf(ang);
        float v = src[d] + pe;
        xr[d] = v;
        xo[d] = __float2bfloat16(v);
    }
}

__global__ __launch_bounds__(256) void ca_part_kernel(
    const float* __restrict__ ca_b_in, const float* __restrict__ ca_w_out,
    float* __restrict__ part)
{
    const int idx = blockIdx.x * 256 + threadIdx.x;
    const int ks = blockIdx.y;
    const int l = idx >> 10, d = idx & 1023;
    const float* bv = ca_b_in + (size_t)l * 3 * D_ + 2 * D_ + ks * 64;
    const float* wp = ca_w_out + (size_t)l * D_ * D_ + (size_t)(ks * 64) * D_ + d;
    float s = 0.f;
    #pragma unroll 8
    for (int k = 0; k < 64; ++k) s = fmaf(bv[k], wp[(size_t)k * D_], s);
    part[(size_t)ks * (L_ * D_) + idx] = s;
}

__global__ __launch_bounds__(256) void ca_reduce_kernel(
    const float* __restrict__ part, const float* __restrict__ ca_b_out,
    float* __restrict__ out)
{
    const int idx = blockIdx.x * 256 + threadIdx.x;
    float s = ca_b_out[idx];
    #pragma unroll
    for (int ks = 0; ks < 16; ++ks) s += part[(size_t)ks * (L_ * D_) + idx];
    out[idx] = s;
}

// ---------------------------------------------------------------------------
extern "C" void kernel_launch(void* const* d_in, const int* in_sizes, int n_in,
                              void* d_out, int out_size, void* d_ws, size_t ws_size,
                              hipStream_t stream)
{
    const float* obs     = (const float*)d_in[0];
    const float* act     = (const float*)d_in[1];
    const float* in_w1   = (const float*)d_in[2];
    const float* in_b1   = (const float*)d_in[3];
    const float* in_w2   = (const float*)d_in[4];
    const float* in_b2   = (const float*)d_in[5];
    const float* in_w3   = (const float*)d_in[6];
    const float* in_b3   = (const float*)d_in[7];
    const float* act_w1  = (const float*)d_in[8];
    const float* act_b1  = (const float*)d_in[9];
    const float* act_w2  = (const float*)d_in[10];
    const float* act_b2  = (const float*)d_in[11];
    const float* act_w3  = (const float*)d_in[12];
    const float* act_b3  = (const float*)d_in[13];
    const float* out_w1  = (const float*)d_in[14];
    const float* out_b1  = (const float*)d_in[15];
    const float* out_w2  = (const float*)d_in[16];
    const float* out_b2  = (const float*)d_in[17];
    const float* out_w3  = (const float*)d_in[18];
    const float* out_b3  = (const float*)d_in[19];
    const float* sa_w_in = (const float*)d_in[20];
    const float* sa_b_in = (const float*)d_in[21];
    const float* sa_w_out= (const float*)d_in[22];
    const float* sa_b_out= (const float*)d_in[23];
    const float* ca_b_in = (const float*)d_in[25];
    const float* ca_w_out= (const float*)d_in[26];
    const float* ca_b_out= (const float*)d_in[27];
    const float* ff_w1   = (const float*)d_in[28];
    const float* ff_b1   = (const float*)d_in[29];
    const float* ff_w2   = (const float*)d_in[30];
    const float* ff_b2   = (const float*)d_in[31];
    const float* ln1_g   = (const float*)d_in[32];
    const float* ln1_b   = (const float*)d_in[33];
    const float* ln2_g   = (const float*)d_in[34];
    const float* ln2_b   = (const float*)d_in[35];
    const float* ln3_g   = (const float*)d_in[36];
    const float* ln3_b   = (const float*)d_in[37];
    const float* lnf_g   = (const float*)d_in[38];
    const float* lnf_b   = (const float*)d_in[39];

    const int MT = B_ * T_;          // 4092
    const int Mo = B_ * S_;          // 2048
    const int Ma = B_ * (S_ - 1);    // 2044

    char* base = (char*)d_ws;
    size_t used = 0;
    auto alloc = [&](size_t bytes) -> char* {
        char* r = base + used;
        used += (bytes + 255) & ~(size_t)255;
        return r;
    };
    typedef __hip_bfloat16 bf;
    bf* wi1  = (bf*)alloc((size_t)1024 * 64 * 2);
    bf* wi2  = (bf*)alloc((size_t)1024 * 1024 * 2);
    bf* wi3  = (bf*)alloc((size_t)1024 * 1024 * 2);
    bf* wa1  = (bf*)alloc((size_t)1024 * 32 * 2);
    bf* wa2  = (bf*)alloc((size_t)1024 * 1024 * 2);
    bf* wa3  = (bf*)alloc((size_t)1024 * 1024 * 2);
    bf* wo1  = (bf*)alloc((size_t)1024 * 1024 * 2);
    bf* wo2  = (bf*)alloc((size_t)1024 * 1024 * 2);
    bf* wo3  = (bf*)alloc((size_t)16 * 1024 * 2);
    bf* wsin = (bf*)alloc((size_t)L_ * 3072 * 1024 * 2);
    bf* wsout= (bf*)alloc((size_t)L_ * 1024 * 1024 * 2);
    bf* wf1  = (bf*)alloc((size_t)L_ * 4096 * 1024 * 2);
    bf* wf2  = (bf*)alloc((size_t)L_ * 1024 * 4096 * 2);
    bf* obs_bf = (bf*)alloc((size_t)Mo * 64 * 2);
    bf* act_bf = (bf*)alloc((size_t)Ma * 32 * 2);
    bf* x_bf   = (bf*)alloc((size_t)MT * D_ * 2);
    bf* attnb  = (bf*)alloc((size_t)MT * D_ * 2);
    bf* h1b    = (bf*)alloc((size_t)MT * D_ * 2);
    bf* h2b    = (bf*)alloc((size_t)MT * D_ * 2);
    char* shared_rg = alloc((size_t)MT * F_ * 2);   // qkvb (25.1MB) | ffh (33.5MB)
    bf* qkvb = (bf*)shared_rg;
    bf* ffh  = (bf*)shared_rg;
    bf* vt   = (bf*)alloc((size_t)B_ * 1024 * 1024 * 2);
    float* x       = (float*)alloc((size_t)MT * D_ * 4);
    float* y       = (float*)alloc((size_t)MT * D_ * 4);
    float* obs_tok = (float*)alloc((size_t)Mo * D_ * 4);
    float* act_tok = (float*)alloc((size_t)Ma * D_ * 4);
    float* ca      = (float*)alloc((size_t)L_ * D_ * 4);
    float* ca_part = (float*)alloc((size_t)16 * L_ * D_ * 4);
    if (used > ws_size) return;

    auto tw = [&](const float* W, bf* Wt, int K, int N, int Kpad, int batch) {
        dim3 g((N + 31) / 32, (Kpad + 31) / 32, batch);
        transpose_w<<<g, 256, 0, stream>>>(W, Wt, K, N, Kpad);
    };
    auto gemm = [&](const bf* A, const bf* Wt, const float* bias,
                    float* Cf, bf* Cb, int M, int K, int N, int relu) {
        dim3 g((N + 127) / 128, (M + 127) / 128);
        gemm_bf16<<<g, 256, 0, stream>>>(A, Wt, bias, Cf, Cb, M, K, N, relu);
    };

    tw(in_w1,  wi1, 64,   1024, 64,   1);
    tw(in_w2,  wi2, 1024, 1024, 1024, 1);
    tw(in_w3,  wi3, 1024, 1024, 1024, 1);
    tw(act_w1, wa1, 16,   1024, 32,   1);
    tw(act_w2, wa2, 1024, 1024, 1024, 1);
    tw(act_w3, wa3, 1024, 1024, 1024, 1);
    tw(out_w1, wo1, 1024, 1024, 1024, 1);
    tw(out_w2, wo2, 1024, 1024, 1024, 1);
    tw(out_w3, wo3, 1024, 16,   1024, 1);
    tw(sa_w_in,  wsin,  1024, 3072, 1024, L_);
    tw(sa_w_out, wsout, 1024, 1024, 1024, L_);
    tw(ff_w1,    wf1,   1024, 4096, 1024, L_);
    tw(ff_w2,    wf2,   4096, 1024, 4096, L_);

    convert_pad<<<(Mo * 64 + 255) / 256, 256, 0, stream>>>(obs, obs_bf, Mo, 64, 64);
    convert_pad<<<(Ma * 32 + 255) / 256, 256, 0, stream>>>(act, act_bf, Ma, 16, 32);
    ca_part_kernel<<<dim3((L_ * D_) / 256, 16), 256, 0, stream>>>(ca_b_in, ca_w_out, ca_part);
    ca_reduce_kernel<<<(L_ * D_) / 256, 256, 0, stream>>>(ca_part, ca_b_out, ca);

    // ---- input MLPs ----
    gemm(obs_bf, wi1, in_b1, nullptr, h1b, Mo, 64,   D_, 1);
    gemm(h1b,    wi2, in_b2, nullptr, h2b, Mo, D_,   D_, 1);
    gemm(h2b,    wi3, in_b3, obs_tok, nullptr, Mo, D_, D_, 0);
    gemm(act_bf, wa1, act_b1, nullptr, h1b, Ma, 32,  D_, 1);
    gemm(h1b,    wa2, act_b2, nullptr, h2b, Ma, D_,  D_, 1);
    gemm(h2b,    wa3, act_b3, act_tok, nullptr, Ma, D_, D_, 0);

    interleave_pe_kernel<<<MT, 256, 0, stream>>>(obs_tok, act_tok, x, x_bf);

    // ---- decoder layers ----
    for (int l = 0; l < L_; ++l) {
        gemm(x_bf, wsin + (size_t)l * 3072 * 1024, sa_b_in + (size_t)l * 3 * D_,
             nullptr, qkvb, MT, D_, 3 * D_, 0);
        v_transpose<<<dim3(32, 32, B_), 256, 0, stream>>>(qkvb, vt);
        attn_mfma<<<dim3(B_ * H_, 8), 256, 0, stream>>>(qkvb, vt, attnb);
        gemm(attnb, wsout + (size_t)l * 1024 * 1024, sa_b_out + (size_t)l * D_,
             y, nullptr, MT, D_, D_, 0);
        add_ln2_kernel<<<MT, 256, 0, stream>>>(x, y, ca + (size_t)l * D_,
             ln1_g + (size_t)l * D_, ln1_b + (size_t)l * D_,
             ln2_g + (size_t)l * D_, ln2_b + (size_t)l * D_, x_bf);
        gemm(x_bf, wf1 + (size_t)l * 4096 * 1024, ff_b1 + (size_t)l * F_,
             nullptr, ffh, MT, D_, F_, 1);
        gemm(ffh, wf2 + (size_t)l * 1024 * 4096, ff_b2 + (size_t)l * D_,
             y, nullptr, MT, F_, D_, 0);
        add_ln_kernel<<<MT, 256, 0, stream>>>(x, y, 0,
             ln3_g + (size_t)l * D_, ln3_b + (size_t)l * D_, x_bf);
    }

    // ---- final norm + output MLP ----
    add_ln_kernel<<<MT, 256, 0, stream>>>(x, nullptr, 0, lnf_g, lnf_b, x_bf);
    gemm(x_bf, wo1, out_b1, nullptr, h1b, MT, D_, D_, 1);
    gemm(h1b,  wo2, out_b2, nullptr, h2b, MT, D_, D_, 1);
    gemm(h2b,  wo3, out_b3, (float*)d_out, nullptr, MT, D_, 16, 0);
}